// Round 8
// baseline (296.917 us; speedup 1.0000x reference)
//
#include <hip/hip_runtime.h>

#define TSTEPS 100
#define BC     16
#define NBLK   (16384/BC)   // 1024 blocks

typedef __attribute__((ext_vector_type(8))) short bf16x8;
typedef __attribute__((ext_vector_type(4))) short s16x4;
typedef __attribute__((ext_vector_type(4))) float f32x4;
typedef __attribute__((ext_vector_type(2))) float f32x2;

// d_ws layout: ushort view for bf16 frags, float view for biases
#define WS_WHH0_U 0         // 16384 ushort
#define WS_WIH1_U 16384
#define WS_WHH1_U 32768
#define WS_WIH0_U 49152     // 8192 ushort -> ends at byte 114688
#define WS_B0_F   28672     // float idx (byte 114688)
#define WS_B1_F   28928     // ends at byte 116736
#define WS_XF_U   65536     // xfrag area, byte 131072; 1024*100*64 ushorts
#define WS_NEED   (131072 + (size_t)NBLK * TSTEPS * 64 * 2)

#define MFMA(A,B,C) __builtin_amdgcn_mfma_f32_16x16x32_bf16(A,B,C,0,0,0)
#define LOG2E 1.4426950408889634f

// RNE (one-shot formatting only)
__device__ __forceinline__ unsigned short f2bf_rne(float f) {
    unsigned int u = __float_as_uint(f);
    u += 0x7fffu + ((u >> 16) & 1u);
    return (unsigned short)(u >> 16);
}
// hot-loop: round-nearest-ties-up, 2 VALU ops
__device__ __forceinline__ unsigned short f2bf(float f) {
    return (unsigned short)((__float_as_uint(f) + 0x8000u) >> 16);
}
// ---- f32x2 packed activation helpers (v_pk_* algebra, scalar trans) ----
__device__ __forceinline__ f32x2 exp2v(f32x2 y) {
    return (f32x2){__builtin_amdgcn_exp2f(y.x), __builtin_amdgcn_exp2f(y.y)};
}
__device__ __forceinline__ f32x2 rcpv(f32x2 y) {
    return (f32x2){__builtin_amdgcn_rcpf(y.x), __builtin_amdgcn_rcpf(y.y)};
}
// y = -L*(x+b) prescaled:  sigmoid = 1/(1+2^y)
__device__ __forceinline__ f32x2 sigv(f32x2 y) {
    return rcpv((f32x2){1.f, 1.f} + exp2v(y));
}
// y = 2L*(x+b) prescaled:  tanh = 1 - 2/(2^y+1)
__device__ __forceinline__ f32x2 tanhv(f32x2 y) {
    const f32x2 e = exp2v(y);
    return (f32x2){1.f, 1.f} - (f32x2){2.f, 2.f} * rcpv(e + (f32x2){1.f, 1.f});
}
// lgkm-only barrier: keeps global prefetch (vmcnt) in flight across the sync
__device__ __forceinline__ void bar_lds() {
    asm volatile("s_waitcnt lgkmcnt(0)\n\ts_barrier" ::: "memory");
}

// One-shot: weights into per-lane MFMA B-frag order (bf16) + fused biases.
// Frag (ug,G,kc): lane l, elem j <-> W[row=G*64+ug*16+(l&15)][k=kc*32+(l>>4)*8+j]
__global__ void reorder_w(const float* __restrict__ Wih0, const float* __restrict__ Whh0,
                          const float* __restrict__ bih0, const float* __restrict__ bhh0,
                          const float* __restrict__ Wih1, const float* __restrict__ Whh1,
                          const float* __restrict__ bih1, const float* __restrict__ bhh1,
                          unsigned short* __restrict__ wsu, float* __restrict__ wsf)
{
    const int idx = blockIdx.x * 256 + threadIdx.x;   // 0..24575
    if (idx < 16384) {
        const int j = idx & 7, lane = (idx >> 3) & 63, kc = (idx >> 9) & 1,
                  G = (idx >> 10) & 3, ug = (idx >> 12) & 3;
        const int row = G * 64 + ug * 16 + (lane & 15);
        const int k   = kc * 32 + (lane >> 4) * 8 + j;
        wsu[WS_WHH0_U + idx] = f2bf_rne(Whh0[row * 64 + k]);
        wsu[WS_WIH1_U + idx] = f2bf_rne(Wih1[row * 64 + k]);
        wsu[WS_WHH1_U + idx] = f2bf_rne(Whh1[row * 64 + k]);
    }
    if (idx < 8192) {
        const int j = idx & 7, lane = (idx >> 3) & 63, G = (idx >> 9) & 3, ug = (idx >> 11) & 3;
        const int row = G * 64 + ug * 16 + (lane & 15);
        // rows k>=4 are EXACT zeros -> main kernel may feed garbage A there
        const float v = ((lane >> 4) == 0 && j < 4) ? Wih0[row * 4 + j] : 0.0f;
        wsu[WS_WIH0_U + idx] = f2bf_rne(v);
    }
    if (idx < 256) {
        wsf[WS_B0_F + idx] = bih0[idx] + bhh0[idx];
        wsf[WS_B1_F + idx] = bih1[idx] + bhh1[idx];
    }
}

// One-shot: x -> bf16 in A-frag-ready order. [tile][t][m 0..15][4 bf16]
__global__ void prep_xfrag(const float* __restrict__ x, unsigned short* __restrict__ xf) {
    const int idx = blockIdx.x * 256 + threadIdx.x;      // tile*1600 + m*100 + t
    const int t    = idx % TSTEPS;
    const int m    = (idx / TSTEPS) & 15;
    const int tile = idx / (TSTEPS * 16);
    const float4 v = *(const float4*)(x + ((size_t)(tile * 16 + m) * TSTEPS + t) * 4);
    const s16x4 o = {(short)f2bf_rne(v.x), (short)f2bf_rne(v.y),
                     (short)f2bf_rne(v.z), (short)f2bf_rne(v.w)};
    *(s16x4*)(xf + ((size_t)(tile * TSTEPS + t) * 16 + m) * 4) = o;
}

// 4-wave blocks; (256,2): VGPR cap 256 -> weights stay AGPR/VGPR-resident
// (round-5 lesson: cap 128 -> 4GB scratch spill).
template<bool XPRE>
__global__ __launch_bounds__(256, 2) void lstm2_mfma(
    const float* __restrict__ x,
    const unsigned short* __restrict__ wsu, const float* __restrict__ wsf,
    const float* __restrict__ gam, const float* __restrict__ bet,
    const float* __restrict__ Wfc, const float* __restrict__ bfc,
    float* __restrict__ out)
{
    // Fragment-native h store: element (m,k) at byte
    //   kc*1024 + ((k>>3)&3)*256 + m*16 + (k&7)*2
    // => A-frag read for lane l = bytes [l*16, l*16+16) (+1024 for kc=1):
    //    sequential across the wave, zero read conflicts.
    __shared__ __align__(16) unsigned short H0[1024];   // 2 KB
    __shared__ __align__(16) unsigned short H1[1024];
    __shared__ float H1F[BC * 65];   // f32 h1 for LN epilogue (last step only)

    const int tid  = threadIdx.x;
    const int lane = tid & 63;
    const int ug   = __builtin_amdgcn_readfirstlane(tid >> 6); // 0..3 unit-group
    const int ln15 = lane & 15, lg = lane >> 4;
    const int bblk = blockIdx.x * BC;

    // ---- resident weight B-fragments (one-time) ----
    bf16x8 Bhh0[4][2], Bih1[4][2], Bhh1[4][2], Bih0[4];
    #pragma unroll
    for (int G = 0; G < 4; ++G) {
        #pragma unroll
        for (int kc = 0; kc < 2; ++kc) {
            const int f = ((ug * 4 + G) * 2 + kc) * 512 + lane * 8;
            Bhh0[G][kc] = *(const bf16x8*)(wsu + WS_WHH0_U + f);
            Bih1[G][kc] = *(const bf16x8*)(wsu + WS_WIH1_U + f);
            Bhh1[G][kc] = *(const bf16x8*)(wsu + WS_WHH1_U + f);
        }
        Bih0[G] = *(const bf16x8*)(wsu + WS_WIH0_U + (ug * 4 + G) * 512 + lane * 8);
    }
    // bias folded into prescaled activation constants:
    // sigmoid arg y=-L*(x+b), tanh arg y=2L*(x+b)
    f32x2 lb0[4], lb1[4];
    #pragma unroll
    for (int G = 0; G < 4; ++G) {
        const float b0 = wsf[WS_B0_F + G * 64 + ug * 16 + ln15];
        const float b1 = wsf[WS_B1_F + G * 64 + ug * 16 + ln15];
        const float s0 = (G == 2) ? (2.0f * LOG2E) * b0 : -LOG2E * b0;
        const float s1 = (G == 2) ? (2.0f * LOG2E) * b1 : -LOG2E * b1;
        lb0[G] = (f32x2){s0, s0};
        lb1[G] = (f32x2){s1, s1};
    }
    const f32x2 nL2 = {-LOG2E, -LOG2E};
    const f32x2 L22 = {2.0f * LOG2E, 2.0f * LOG2E};
    const f32x4 zero4 = {0.f, 0.f, 0.f, 0.f};

    // ---- t-invariant LDS byte addresses ----
    const int kcw = ug >> 1;
    const int lgc = ((ug & 1) << 1) + (ln15 >> 3);
    const unsigned wbase = (unsigned)(kcw * 1024 + lgc * 256 + lg * 64 + (ln15 & 7) * 2);
    const unsigned rbase = (unsigned)(lane * 16);
    char* const H0c = (char*)H0;
    char* const H1c = (char*)H1;

    f32x2 c0v[2] = {{0.f,0.f},{0.f,0.f}}, c1v[2] = {{0.f,0.f},{0.f,0.f}};
    const bf16x8 zfrag = {0,0,0,0,0,0,0,0};
    bf16x8 A0[2], A1[2];
    A0[0] = zfrag; A0[1] = zfrag; A1[0] = zfrag; A1[1] = zfrag;   // h(-1)=0

    // ---- x input: either precomputed bf16 frags (XPRE) or f32 + convert ----
    const unsigned short* xfp = wsu + WS_XF_U + (size_t)blockIdx.x * (TSTEPS * 64) + ln15 * 4;
    const float* xb = x + (size_t)(bblk + ln15) * (TSTEPS * 4);
    s16x4 xv = {0,0,0,0};
    float4 xf4;
    if (XPRE) xv = *(const s16x4*)(xfp);       // all lanes; lanes lg>0 replicate,
    else      xf4 = *(const float4*)(xb);      // their products hit zero B rows

    union U8 { bf16x8 v8; struct { s16x4 lo, hi; } p; };

    for (int t = 0; t < TSTEPS; ++t) {
        // ---------- layer 0 ----------
        bf16x8 ax;
        if (XPRE) {
            U8 u; u.p.lo = xv; u.p.hi = xv;    // hi half: k>=8 rows of B are 0
            ax = u.v8;
        } else {
            ax = zfrag;
            if (lg == 0) {
                ax[0] = (short)f2bf_rne(xf4.x); ax[1] = (short)f2bf_rne(xf4.y);
                ax[2] = (short)f2bf_rne(xf4.z); ax[3] = (short)f2bf_rne(xf4.w);
            }
        }
        f32x4 acc[4];
        #pragma unroll
        for (int G = 0; G < 4; ++G) {
            acc[G] = MFMA(A0[0], Bhh0[G][0], zero4);
            acc[G] = MFMA(A0[1], Bhh0[G][1], acc[G]);
            acc[G] = MFMA(ax,    Bih0[G],    acc[G]);
        }
        if (t + 1 < TSTEPS) {                   // prefetch next x
            if (XPRE) xv = *(const s16x4*)(xfp + (t + 1) * 64);
            else      xf4 = *(const float4*)(xb + (t + 1) * 4);
        }

        #pragma unroll
        for (int p = 0; p < 2; ++p) {
            const f32x2 ig = sigv ((f32x2){acc[0][2*p], acc[0][2*p+1]} * nL2 + lb0[0]);
            const f32x2 fg = sigv ((f32x2){acc[1][2*p], acc[1][2*p+1]} * nL2 + lb0[1]);
            const f32x2 gg = tanhv((f32x2){acc[2][2*p], acc[2][2*p+1]} * L22 + lb0[2]);
            const f32x2 og = sigv ((f32x2){acc[3][2*p], acc[3][2*p+1]} * nL2 + lb0[3]);
            const f32x2 c  = fg * c0v[p] + ig * gg;
            c0v[p] = c;
            const f32x2 h = og * tanhv(c * L22);
            *(unsigned short*)(H0c + wbase + (2*p)   * 16) = f2bf(h.x);
            *(unsigned short*)(H0c + wbase + (2*p+1) * 16) = f2bf(h.y);
        }
        bar_lds();   // publish h0
        A0[0] = *(const bf16x8*)(H0c + rbase);
        A0[1] = *(const bf16x8*)(H0c + rbase + 1024);

        // ---------- layer 1 ----------
        #pragma unroll
        for (int G = 0; G < 4; ++G) {
            acc[G] = MFMA(A0[0], Bih1[G][0], zero4);
            acc[G] = MFMA(A0[1], Bih1[G][1], acc[G]);
            acc[G] = MFMA(A1[0], Bhh1[G][0], acc[G]);
            acc[G] = MFMA(A1[1], Bhh1[G][1], acc[G]);
        }
        #pragma unroll
        for (int p = 0; p < 2; ++p) {
            const f32x2 ig = sigv ((f32x2){acc[0][2*p], acc[0][2*p+1]} * nL2 + lb1[0]);
            const f32x2 fg = sigv ((f32x2){acc[1][2*p], acc[1][2*p+1]} * nL2 + lb1[1]);
            const f32x2 gg = tanhv((f32x2){acc[2][2*p], acc[2][2*p+1]} * L22 + lb1[2]);
            const f32x2 og = sigv ((f32x2){acc[3][2*p], acc[3][2*p+1]} * nL2 + lb1[3]);
            const f32x2 c  = fg * c1v[p] + ig * gg;
            c1v[p] = c;
            const f32x2 h = og * tanhv(c * L22);
            *(unsigned short*)(H1c + wbase + (2*p)   * 16) = f2bf(h.x);
            *(unsigned short*)(H1c + wbase + (2*p+1) * 16) = f2bf(h.y);
            if (t == TSTEPS - 1) {
                H1F[(lg * 4 + 2*p)     * 65 + ug * 16 + ln15] = h.x;
                H1F[(lg * 4 + 2*p + 1) * 65 + ug * 16 + ln15] = h.y;
            }
        }
        bar_lds();   // publish h1
        A1[0] = *(const bf16x8*)(H1c + rbase);
        A1[1] = *(const bf16x8*)(H1c + rbase + 1024);
    }

    // ---------- LayerNorm + FC on h1(T-1), f32 path ----------
    if (tid < BC) {
        const int b = tid;
        float hr[64];
        float mu = 0.f;
        #pragma unroll
        for (int k = 0; k < 64; ++k) { hr[k] = H1F[b * 65 + k]; mu += hr[k]; }
        mu *= (1.f / 64.f);
        float var = 0.f;
        #pragma unroll
        for (int k = 0; k < 64; ++k) { const float d = hr[k] - mu; var = fmaf(d, d, var); }
        var *= (1.f / 64.f);
        const float rs = rsqrtf(var + 1e-5f);
        float o0 = bfc[0], o1 = bfc[1];
        #pragma unroll
        for (int k = 0; k < 64; ++k) {
            const float nk = (hr[k] - mu) * rs * gam[k] + bet[k];
            o0 = fmaf(nk, Wfc[k],      o0);
            o1 = fmaf(nk, Wfc[64 + k], o1);
        }
        out[(size_t)(bblk + b) * 2 + 0] = o0;
        out[(size_t)(bblk + b) * 2 + 1] = o1;
    }
}

extern "C" void kernel_launch(void* const* d_in, const int* in_sizes, int n_in,
                              void* d_out, int out_size, void* d_ws, size_t ws_size,
                              hipStream_t stream) {
    (void)in_sizes; (void)n_in; (void)out_size;
    const float* x    = (const float*)d_in[0];
    const float* Wih0 = (const float*)d_in[1];
    const float* Whh0 = (const float*)d_in[2];
    const float* bih0 = (const float*)d_in[3];
    const float* bhh0 = (const float*)d_in[4];
    const float* Wih1 = (const float*)d_in[5];
    const float* Whh1 = (const float*)d_in[6];
    const float* bih1 = (const float*)d_in[7];
    const float* bhh1 = (const float*)d_in[8];
    const float* gam  = (const float*)d_in[9];
    const float* bet  = (const float*)d_in[10];
    const float* Wfc  = (const float*)d_in[11];
    const float* bfc  = (const float*)d_in[12];
    unsigned short* wsu = (unsigned short*)d_ws;
    float*          wsf = (float*)d_ws;
    float* out = (float*)d_out;

    hipLaunchKernelGGL(reorder_w, dim3(96), dim3(256), 0, stream,
                       Wih0, Whh0, bih0, bhh0, Wih1, Whh1, bih1, bhh1, wsu, wsf);
    if (ws_size >= WS_NEED) {
        hipLaunchKernelGGL(prep_xfrag, dim3(NBLK * 16 * TSTEPS / 256), dim3(256), 0, stream,
                           x, wsu + WS_XF_U);
        hipLaunchKernelGGL((lstm2_mfma<true>), dim3(NBLK), dim3(256), 0, stream,
                           x, wsu, wsf, gam, bet, Wfc, bfc, out);
    } else {
        hipLaunchKernelGGL((lstm2_mfma<false>), dim3(NBLK), dim3(256), 0, stream,
                           x, wsu, wsf, gam, bet, Wfc, bfc, out);
    }
}

// Round 9
// 282.171 us; speedup vs baseline: 1.0523x; 1.0523x over previous
//
#include <hip/hip_runtime.h>

#define TSTEPS 100
#define BC     16
#define NBLK   (16384/BC)   // 1024 blocks

typedef __attribute__((ext_vector_type(8))) short bf16x8;
typedef __attribute__((ext_vector_type(4))) short s16x4;
typedef __attribute__((ext_vector_type(4))) float f32x4;
typedef __attribute__((ext_vector_type(2))) float f32x2;

// d_ws layout: ushort view for bf16 frags, float view for biases
#define WS_WHH0_U 0         // 16384 ushort
#define WS_WIH1_U 16384
#define WS_WHH1_U 32768
#define WS_WIH0_U 49152     // 8192 ushort -> ends at byte 114688
#define WS_B0_F   28672     // float idx (byte 114688)
#define WS_B1_F   28928     // ends at byte 116736
#define WS_XF_U   65536     // xfrag area, byte 131072; 1024*100*64 ushorts
#define WS_NEED   (131072 + (size_t)NBLK * TSTEPS * 64 * 2)

#define MFMA(A,B,C) __builtin_amdgcn_mfma_f32_16x16x32_bf16(A,B,C,0,0,0)
#define LOG2E 1.4426950408889634f

// RNE (one-shot formatting only)
__device__ __forceinline__ unsigned short f2bf_rne(float f) {
    unsigned int u = __float_as_uint(f);
    u += 0x7fffu + ((u >> 16) & 1u);
    return (unsigned short)(u >> 16);
}
// hot-loop: round-nearest-ties-up, 2 VALU ops
__device__ __forceinline__ unsigned short f2bf(float f) {
    return (unsigned short)((__float_as_uint(f) + 0x8000u) >> 16);
}
// ---- f32x2 packed activation helpers (v_pk_* algebra, scalar trans) ----
__device__ __forceinline__ f32x2 exp2v(f32x2 y) {
    return (f32x2){__builtin_amdgcn_exp2f(y.x), __builtin_amdgcn_exp2f(y.y)};
}
__device__ __forceinline__ f32x2 rcpv(f32x2 y) {
    return (f32x2){__builtin_amdgcn_rcpf(y.x), __builtin_amdgcn_rcpf(y.y)};
}
// y = -L*(x+b) prescaled:  sigmoid = 1/(1+2^y)
__device__ __forceinline__ f32x2 sigv(f32x2 y) {
    return rcpv((f32x2){1.f, 1.f} + exp2v(y));
}
// y = 2L*(x+b) prescaled:  tanh = 1 - 2/(2^y+1)
__device__ __forceinline__ f32x2 tanhv(f32x2 y) {
    const f32x2 e = exp2v(y);
    return (f32x2){1.f, 1.f} - (f32x2){2.f, 2.f} * rcpv(e + (f32x2){1.f, 1.f});
}
// lgkm-only barrier: keeps global prefetch (vmcnt) in flight across the sync
__device__ __forceinline__ void bar_lds() {
    asm volatile("s_waitcnt lgkmcnt(0)\n\ts_barrier" ::: "memory");
}

// One-shot: weights into per-lane MFMA B-frag order (bf16) + fused biases.
// Frag (ug,G,kc): lane l, elem j <-> W[row=G*64+ug*16+(l&15)][k=kc*32+(l>>4)*8+j]
__global__ void reorder_w(const float* __restrict__ Wih0, const float* __restrict__ Whh0,
                          const float* __restrict__ bih0, const float* __restrict__ bhh0,
                          const float* __restrict__ Wih1, const float* __restrict__ Whh1,
                          const float* __restrict__ bih1, const float* __restrict__ bhh1,
                          unsigned short* __restrict__ wsu, float* __restrict__ wsf)
{
    const int idx = blockIdx.x * 256 + threadIdx.x;   // 0..24575
    if (idx < 16384) {
        const int j = idx & 7, lane = (idx >> 3) & 63, kc = (idx >> 9) & 1,
                  G = (idx >> 10) & 3, ug = (idx >> 12) & 3;
        const int row = G * 64 + ug * 16 + (lane & 15);
        const int k   = kc * 32 + (lane >> 4) * 8 + j;
        wsu[WS_WHH0_U + idx] = f2bf_rne(Whh0[row * 64 + k]);
        wsu[WS_WIH1_U + idx] = f2bf_rne(Wih1[row * 64 + k]);
        wsu[WS_WHH1_U + idx] = f2bf_rne(Whh1[row * 64 + k]);
    }
    if (idx < 8192) {
        const int j = idx & 7, lane = (idx >> 3) & 63, G = (idx >> 9) & 3, ug = (idx >> 11) & 3;
        const int row = G * 64 + ug * 16 + (lane & 15);
        // rows k>=4 are EXACT zeros -> main kernel may feed garbage A there
        const float v = ((lane >> 4) == 0 && j < 4) ? Wih0[row * 4 + j] : 0.0f;
        wsu[WS_WIH0_U + idx] = f2bf_rne(v);
    }
    if (idx < 256) {
        wsf[WS_B0_F + idx] = bih0[idx] + bhh0[idx];
        wsf[WS_B1_F + idx] = bih1[idx] + bhh1[idx];
    }
}

// One-shot: x -> bf16 in A-frag-ready order. [tile][t][m 0..15][4 bf16]
__global__ void prep_xfrag(const float* __restrict__ x, unsigned short* __restrict__ xf) {
    const int idx = blockIdx.x * 256 + threadIdx.x;      // tile*1600 + m*100 + t
    const int t    = idx % TSTEPS;
    const int m    = (idx / TSTEPS) & 15;
    const int tile = idx / (TSTEPS * 16);
    const float4 v = *(const float4*)(x + ((size_t)(tile * 16 + m) * TSTEPS + t) * 4);
    const s16x4 o = {(short)f2bf_rne(v.x), (short)f2bf_rne(v.y),
                     (short)f2bf_rne(v.z), (short)f2bf_rne(v.w)};
    *(s16x4*)(xf + ((size_t)(tile * TSTEPS + t) * 16 + m) * 4) = o;
}

// Skewed-recurrence step: computes L1(T) and L0(T+1) from the same published
// state {h0(T), h1(T-1)}, ONE barrier per time-step. P = T&1 (compile-time).
// h0(s) lives at byte (s&1)*2048; h1(s) at 4096 + (s&1)*2048.
#define STEP_BODY(T, P)                                                          \
  {                                                                              \
    f32x4 acc1[4];                                                               \
    _Pragma("unroll") for (int G = 0; G < 4; ++G) {                              \
      acc1[G] = MFMA(A0[0], Bih1[G][0], zero4);                                  \
      acc1[G] = MFMA(A0[1], Bih1[G][1], acc1[G]);                                \
      acc1[G] = MFMA(A1[0], Bhh1[G][0], acc1[G]);                                \
      acc1[G] = MFMA(A1[1], Bhh1[G][1], acc1[G]);                                \
    }                                                                            \
    bf16x8 ax;                                                                   \
    if (XPRE) { U8 u; u.p.lo = xv; u.p.hi = xv; ax = u.v8; }                     \
    else {                                                                       \
      ax = zfrag;                                                                \
      if (lg == 0) {                                                             \
        ax[0] = (short)f2bf_rne(xf4.x); ax[1] = (short)f2bf_rne(xf4.y);          \
        ax[2] = (short)f2bf_rne(xf4.z); ax[3] = (short)f2bf_rne(xf4.w);          \
      }                                                                          \
    }                                                                            \
    f32x4 acc0[4];                                                               \
    _Pragma("unroll") for (int G = 0; G < 4; ++G) {                              \
      acc0[G] = MFMA(A0[0], Bhh0[G][0], zero4);                                  \
      acc0[G] = MFMA(A0[1], Bhh0[G][1], acc0[G]);                                \
      acc0[G] = MFMA(ax,    Bih0[G],    acc0[G]);                                \
    }                                                                            \
    if ((T) + 2 < TSTEPS) {                                                      \
      if (XPRE) xv  = *(const s16x4*)(xfp + ((T) + 2) * 64);                     \
      else      xf4 = *(const float4*)(xb + ((T) + 2) * 4);                      \
    }                                                                            \
    _Pragma("unroll") for (int p = 0; p < 2; ++p) {  /* L0(T+1) gates */         \
      const f32x2 ig = sigv ((f32x2){acc0[0][2*p], acc0[0][2*p+1]} * nL2 + lb0[0]); \
      const f32x2 fg = sigv ((f32x2){acc0[1][2*p], acc0[1][2*p+1]} * nL2 + lb0[1]); \
      const f32x2 gg = tanhv((f32x2){acc0[2][2*p], acc0[2][2*p+1]} * L22 + lb0[2]); \
      const f32x2 og = sigv ((f32x2){acc0[3][2*p], acc0[3][2*p+1]} * nL2 + lb0[3]); \
      const f32x2 c  = fg * c0v[p] + ig * gg;                                    \
      c0v[p] = c;                                                                \
      const f32x2 h = og * tanhv(c * L22);                                       \
      *(unsigned short*)(HBc + (((P)^1)<<11) + wbase + (2*p)  *16) = f2bf(h.x);  \
      *(unsigned short*)(HBc + (((P)^1)<<11) + wbase + (2*p+1)*16) = f2bf(h.y);  \
    }                                                                            \
    _Pragma("unroll") for (int p = 0; p < 2; ++p) {  /* L1(T) gates */           \
      const f32x2 ig = sigv ((f32x2){acc1[0][2*p], acc1[0][2*p+1]} * nL2 + lb1[0]); \
      const f32x2 fg = sigv ((f32x2){acc1[1][2*p], acc1[1][2*p+1]} * nL2 + lb1[1]); \
      const f32x2 gg = tanhv((f32x2){acc1[2][2*p], acc1[2][2*p+1]} * L22 + lb1[2]); \
      const f32x2 og = sigv ((f32x2){acc1[3][2*p], acc1[3][2*p+1]} * nL2 + lb1[3]); \
      const f32x2 c  = fg * c1v[p] + ig * gg;                                    \
      c1v[p] = c;                                                                \
      const f32x2 h = og * tanhv(c * L22);                                       \
      *(unsigned short*)(HBc + 4096 + ((P)<<11) + wbase + (2*p)  *16) = f2bf(h.x); \
      *(unsigned short*)(HBc + 4096 + ((P)<<11) + wbase + (2*p+1)*16) = f2bf(h.y); \
    }                                                                            \
    bar_lds();                                                                   \
    A0[0] = *(const bf16x8*)(HBc + (((P)^1)<<11) + rbase);                       \
    A0[1] = *(const bf16x8*)(HBc + (((P)^1)<<11) + rbase + 1024);                \
    A1[0] = *(const bf16x8*)(HBc + 4096 + ((P)<<11) + rbase);                    \
    A1[1] = *(const bf16x8*)(HBc + 4096 + ((P)<<11) + rbase + 1024);             \
  }

// 4-wave blocks; (256,2): VGPR cap 256 -> weights stay AGPR/VGPR-resident
// (round-5 lesson: cap 128 -> 4GB scratch spill).
template<bool XPRE>
__global__ __launch_bounds__(256, 2) void lstm2_mfma(
    const float* __restrict__ x,
    const unsigned short* __restrict__ wsu, const float* __restrict__ wsf,
    const float* __restrict__ gam, const float* __restrict__ bet,
    const float* __restrict__ Wfc, const float* __restrict__ bfc,
    float* __restrict__ out)
{
    // Fragment-native h store (per 2KB buffer): element (m,k) at byte
    //   kc*1024 + ((k>>3)&3)*256 + m*16 + (k&7)*2
    // => A-frag read for lane l = bytes [l*16, l*16+16) (+1024 for kc=1):
    //    sequential across the wave, zero read conflicts.
    // 4 ping-pong buffers: h0 p0/p1 @0/@2048, h1 p0/p1 @4096/@6144.
    __shared__ __align__(16) unsigned short HB[4096];   // 8 KB
    __shared__ float H1F[BC * 65];   // f32 h1 for LN epilogue (last step only)

    const int tid  = threadIdx.x;
    const int lane = tid & 63;
    const int ug   = __builtin_amdgcn_readfirstlane(tid >> 6); // 0..3 unit-group
    const int ln15 = lane & 15, lg = lane >> 4;
    const int bblk = blockIdx.x * BC;

    // ---- resident weight B-fragments (one-time) ----
    bf16x8 Bhh0[4][2], Bih1[4][2], Bhh1[4][2], Bih0[4];
    #pragma unroll
    for (int G = 0; G < 4; ++G) {
        #pragma unroll
        for (int kc = 0; kc < 2; ++kc) {
            const int f = ((ug * 4 + G) * 2 + kc) * 512 + lane * 8;
            Bhh0[G][kc] = *(const bf16x8*)(wsu + WS_WHH0_U + f);
            Bih1[G][kc] = *(const bf16x8*)(wsu + WS_WIH1_U + f);
            Bhh1[G][kc] = *(const bf16x8*)(wsu + WS_WHH1_U + f);
        }
        Bih0[G] = *(const bf16x8*)(wsu + WS_WIH0_U + (ug * 4 + G) * 512 + lane * 8);
    }
    // bias folded into prescaled activation constants:
    // sigmoid arg y=-L*(x+b), tanh arg y=2L*(x+b)
    f32x2 lb0[4], lb1[4];
    #pragma unroll
    for (int G = 0; G < 4; ++G) {
        const float b0 = wsf[WS_B0_F + G * 64 + ug * 16 + ln15];
        const float b1 = wsf[WS_B1_F + G * 64 + ug * 16 + ln15];
        const float s0 = (G == 2) ? (2.0f * LOG2E) * b0 : -LOG2E * b0;
        const float s1 = (G == 2) ? (2.0f * LOG2E) * b1 : -LOG2E * b1;
        lb0[G] = (f32x2){s0, s0};
        lb1[G] = (f32x2){s1, s1};
    }
    const f32x2 nL2 = {-LOG2E, -LOG2E};
    const f32x2 L22 = {2.0f * LOG2E, 2.0f * LOG2E};
    const f32x4 zero4 = {0.f, 0.f, 0.f, 0.f};

    // ---- t-invariant LDS byte addresses (within a 2KB buffer) ----
    const int kcw = ug >> 1;
    const int lgc = ((ug & 1) << 1) + (ln15 >> 3);
    const unsigned wbase = (unsigned)(kcw * 1024 + lgc * 256 + lg * 64 + (ln15 & 7) * 2);
    const unsigned rbase = (unsigned)(lane * 16);
    char* const HBc = (char*)HB;

    f32x2 c0v[2] = {{0.f,0.f},{0.f,0.f}}, c1v[2] = {{0.f,0.f},{0.f,0.f}};
    const bf16x8 zfrag = {0,0,0,0,0,0,0,0};
    bf16x8 A0[2], A1[2];
    A1[0] = zfrag; A1[1] = zfrag;   // h1(-1) = 0

    // ---- x input: precomputed bf16 frags (XPRE) or f32 + convert ----
    const unsigned short* xfp = wsu + WS_XF_U + (size_t)blockIdx.x * (TSTEPS * 64) + ln15 * 4;
    const float* xb = x + (size_t)(bblk + ln15) * (TSTEPS * 4);
    s16x4 xv = {0,0,0,0};
    float4 xf4;
    if (XPRE) xv = *(const s16x4*)(xfp);       // lanes lg>0 replicate; their
    else      xf4 = *(const float4*)(xb);      // products hit zero B rows

    union U8 { bf16x8 v8; struct { s16x4 lo, hi; } p; };

    // ---- prologue: L0(0) = x-term only (h0(-1)=0) -> publish h0(0) @parity0
    {
        bf16x8 ax;
        if (XPRE) { U8 u; u.p.lo = xv; u.p.hi = xv; ax = u.v8; }
        else {
            ax = zfrag;
            if (lg == 0) {
                ax[0] = (short)f2bf_rne(xf4.x); ax[1] = (short)f2bf_rne(xf4.y);
                ax[2] = (short)f2bf_rne(xf4.z); ax[3] = (short)f2bf_rne(xf4.w);
            }
        }
        f32x4 acc[4];
        #pragma unroll
        for (int G = 0; G < 4; ++G) acc[G] = MFMA(ax, Bih0[G], zero4);
        if (XPRE) xv  = *(const s16x4*)(xfp + 64);       // prefetch x(1)
        else      xf4 = *(const float4*)(xb + 4);
        #pragma unroll
        for (int p = 0; p < 2; ++p) {
            const f32x2 ig = sigv ((f32x2){acc[0][2*p], acc[0][2*p+1]} * nL2 + lb0[0]);
            const f32x2 fg = sigv ((f32x2){acc[1][2*p], acc[1][2*p+1]} * nL2 + lb0[1]);
            const f32x2 gg = tanhv((f32x2){acc[2][2*p], acc[2][2*p+1]} * L22 + lb0[2]);
            const f32x2 og = sigv ((f32x2){acc[3][2*p], acc[3][2*p+1]} * nL2 + lb0[3]);
            const f32x2 c  = fg * c0v[p] + ig * gg;
            c0v[p] = c;
            const f32x2 h = og * tanhv(c * L22);
            *(unsigned short*)(HBc + wbase + (2*p)  *16) = f2bf(h.x);
            *(unsigned short*)(HBc + wbase + (2*p+1)*16) = f2bf(h.y);
        }
        bar_lds();
        A0[0] = *(const bf16x8*)(HBc + rbase);
        A0[1] = *(const bf16x8*)(HBc + rbase + 1024);
    }

    // ---- skewed main loop: 99 bodies (t = 0..98), one barrier each ----
    int t = 0;
    #pragma unroll 1
    for (int tb = 0; tb < (TSTEPS - 1) / 2; ++tb) {   // 49 pairs -> t=0..97
        STEP_BODY(t, 0);
        STEP_BODY(t + 1, 1);
        t += 2;
    }
    STEP_BODY(t, 0);   // t = 98

    // ---- epilogue: L1(99) -> H1F (f32), then LN + FC ----
    {
        f32x4 acc1[4];
        #pragma unroll
        for (int G = 0; G < 4; ++G) {
            acc1[G] = MFMA(A0[0], Bih1[G][0], zero4);
            acc1[G] = MFMA(A0[1], Bih1[G][1], acc1[G]);
            acc1[G] = MFMA(A1[0], Bhh1[G][0], acc1[G]);
            acc1[G] = MFMA(A1[1], Bhh1[G][1], acc1[G]);
        }
        #pragma unroll
        for (int p = 0; p < 2; ++p) {
            const f32x2 ig = sigv ((f32x2){acc1[0][2*p], acc1[0][2*p+1]} * nL2 + lb1[0]);
            const f32x2 fg = sigv ((f32x2){acc1[1][2*p], acc1[1][2*p+1]} * nL2 + lb1[1]);
            const f32x2 gg = tanhv((f32x2){acc1[2][2*p], acc1[2][2*p+1]} * L22 + lb1[2]);
            const f32x2 og = sigv ((f32x2){acc1[3][2*p], acc1[3][2*p+1]} * nL2 + lb1[3]);
            const f32x2 c  = fg * c1v[p] + ig * gg;
            c1v[p] = c;
            const f32x2 h = og * tanhv(c * L22);
            H1F[(lg * 4 + 2*p)     * 65 + ug * 16 + ln15] = h.x;
            H1F[(lg * 4 + 2*p + 1) * 65 + ug * 16 + ln15] = h.y;
        }
        bar_lds();
    }

    if (tid < BC) {
        const int b = tid;
        float hr[64];
        float mu = 0.f;
        #pragma unroll
        for (int k = 0; k < 64; ++k) { hr[k] = H1F[b * 65 + k]; mu += hr[k]; }
        mu *= (1.f / 64.f);
        float var = 0.f;
        #pragma unroll
        for (int k = 0; k < 64; ++k) { const float d = hr[k] - mu; var = fmaf(d, d, var); }
        var *= (1.f / 64.f);
        const float rs = rsqrtf(var + 1e-5f);
        float o0 = bfc[0], o1 = bfc[1];
        #pragma unroll
        for (int k = 0; k < 64; ++k) {
            const float nk = (hr[k] - mu) * rs * gam[k] + bet[k];
            o0 = fmaf(nk, Wfc[k],      o0);
            o1 = fmaf(nk, Wfc[64 + k], o1);
        }
        out[(size_t)(bblk + b) * 2 + 0] = o0;
        out[(size_t)(bblk + b) * 2 + 1] = o1;
    }
}

extern "C" void kernel_launch(void* const* d_in, const int* in_sizes, int n_in,
                              void* d_out, int out_size, void* d_ws, size_t ws_size,
                              hipStream_t stream) {
    (void)in_sizes; (void)n_in; (void)out_size;
    const float* x    = (const float*)d_in[0];
    const float* Wih0 = (const float*)d_in[1];
    const float* Whh0 = (const float*)d_in[2];
    const float* bih0 = (const float*)d_in[3];
    const float* bhh0 = (const float*)d_in[4];
    const float* Wih1 = (const float*)d_in[5];
    const float* Whh1 = (const float*)d_in[6];
    const float* bih1 = (const float*)d_in[7];
    const float* bhh1 = (const float*)d_in[8];
    const float* gam  = (const float*)d_in[9];
    const float* bet  = (const float*)d_in[10];
    const float* Wfc  = (const float*)d_in[11];
    const float* bfc  = (const float*)d_in[12];
    unsigned short* wsu = (unsigned short*)d_ws;
    float*          wsf = (float*)d_ws;
    float* out = (float*)d_out;

    hipLaunchKernelGGL(reorder_w, dim3(96), dim3(256), 0, stream,
                       Wih0, Whh0, bih0, bhh0, Wih1, Whh1, bih1, bhh1, wsu, wsf);
    if (ws_size >= WS_NEED) {
        hipLaunchKernelGGL(prep_xfrag, dim3(NBLK * 16 * TSTEPS / 256), dim3(256), 0, stream,
                           x, wsu + WS_XF_U);
        hipLaunchKernelGGL((lstm2_mfma<true>), dim3(NBLK), dim3(256), 0, stream,
                           x, wsu, wsf, gam, bet, Wfc, bfc, out);
    } else {
        hipLaunchKernelGGL((lstm2_mfma<false>), dim3(NBLK), dim3(256), 0, stream,
                           x, wsu, wsf, gam, bet, Wfc, bfc, out);
    }
}

// Round 10
// 277.455 us; speedup vs baseline: 1.0701x; 1.0170x over previous
//
#include <hip/hip_runtime.h>

#define TSTEPS 100
#define BC     16
#define NBLK   (16384/BC)   // 1024 blocks

typedef __attribute__((ext_vector_type(8))) short bf16x8;
typedef __attribute__((ext_vector_type(4))) short s16x4;
typedef __attribute__((ext_vector_type(4))) float f32x4;
typedef __attribute__((ext_vector_type(2))) float f32x2;

// d_ws layout: ushort view for bf16 frags, float view for biases
#define WS_WHH0_U 0         // 16384 ushort
#define WS_WIH1_U 16384
#define WS_WHH1_U 32768
#define WS_WIH0_U 49152     // 8192 ushort -> ends at byte 114688
#define WS_B0_F   28672     // float idx (byte 114688)
#define WS_B1_F   28928     // ends at byte 116736
#define WS_XF_U   65536     // xfrag area, byte 131072; 1024*100*64 ushorts
#define WS_NEED   (131072 + (size_t)NBLK * TSTEPS * 64 * 2)

#define MFMA(A,B,C) __builtin_amdgcn_mfma_f32_16x16x32_bf16(A,B,C,0,0,0)
#define LOG2E 1.4426950408889634f

// RNE (one-shot formatting only)
__device__ __forceinline__ unsigned short f2bf_rne(float f) {
    unsigned int u = __float_as_uint(f);
    u += 0x7fffu + ((u >> 16) & 1u);
    return (unsigned short)(u >> 16);
}
// hot-loop: round-nearest-ties-up, 2 VALU ops
__device__ __forceinline__ unsigned short f2bf(float f) {
    return (unsigned short)((__float_as_uint(f) + 0x8000u) >> 16);
}
// ---- f32x2 packed activation helpers (v_pk_* algebra, scalar trans) ----
__device__ __forceinline__ f32x2 exp2v(f32x2 y) {
    return (f32x2){__builtin_amdgcn_exp2f(y.x), __builtin_amdgcn_exp2f(y.y)};
}
__device__ __forceinline__ f32x2 rcpv(f32x2 y) {
    return (f32x2){__builtin_amdgcn_rcpf(y.x), __builtin_amdgcn_rcpf(y.y)};
}
// y = -L*(x+b) prescaled:  sigmoid = 1/(1+2^y)
__device__ __forceinline__ f32x2 sigv(f32x2 y) {
    return rcpv((f32x2){1.f, 1.f} + exp2v(y));
}
// y = 2L*(x+b) prescaled:  tanh = 1 - 2/(2^y+1)
__device__ __forceinline__ f32x2 tanhv(f32x2 y) {
    const f32x2 e = exp2v(y);
    return (f32x2){1.f, 1.f} - (f32x2){2.f, 2.f} * rcpv(e + (f32x2){1.f, 1.f});
}
// lgkm-only barrier: keeps global prefetch (vmcnt) in flight across the sync
__device__ __forceinline__ void bar_lds() {
    asm volatile("s_waitcnt lgkmcnt(0)\n\ts_barrier" ::: "memory");
}

// One-shot: weights into per-lane MFMA B-frag order (bf16) + fused biases.
// Frag (ug,G,kc): lane l, elem j <-> W[row=G*64+ug*16+(l&15)][k=kc*32+(l>>4)*8+j]
__global__ void reorder_w(const float* __restrict__ Wih0, const float* __restrict__ Whh0,
                          const float* __restrict__ bih0, const float* __restrict__ bhh0,
                          const float* __restrict__ Wih1, const float* __restrict__ Whh1,
                          const float* __restrict__ bih1, const float* __restrict__ bhh1,
                          unsigned short* __restrict__ wsu, float* __restrict__ wsf)
{
    const int idx = blockIdx.x * 256 + threadIdx.x;   // 0..24575
    if (idx < 16384) {
        const int j = idx & 7, lane = (idx >> 3) & 63, kc = (idx >> 9) & 1,
                  G = (idx >> 10) & 3, ug = (idx >> 12) & 3;
        const int row = G * 64 + ug * 16 + (lane & 15);
        const int k   = kc * 32 + (lane >> 4) * 8 + j;
        wsu[WS_WHH0_U + idx] = f2bf_rne(Whh0[row * 64 + k]);
        wsu[WS_WIH1_U + idx] = f2bf_rne(Wih1[row * 64 + k]);
        wsu[WS_WHH1_U + idx] = f2bf_rne(Whh1[row * 64 + k]);
    }
    if (idx < 8192) {
        const int j = idx & 7, lane = (idx >> 3) & 63, G = (idx >> 9) & 3, ug = (idx >> 11) & 3;
        const int row = G * 64 + ug * 16 + (lane & 15);
        // rows k>=4 are EXACT zeros -> main kernel may feed garbage A there
        const float v = ((lane >> 4) == 0 && j < 4) ? Wih0[row * 4 + j] : 0.0f;
        wsu[WS_WIH0_U + idx] = f2bf_rne(v);
    }
    if (idx < 256) {
        wsf[WS_B0_F + idx] = bih0[idx] + bhh0[idx];
        wsf[WS_B1_F + idx] = bih1[idx] + bhh1[idx];
    }
}

// One-shot: x -> bf16 in A-frag-ready order. [tile][t][m 0..15][4 bf16]
__global__ void prep_xfrag(const float* __restrict__ x, unsigned short* __restrict__ xf) {
    const int idx = blockIdx.x * 256 + threadIdx.x;      // tile*1600 + m*100 + t
    const int t    = idx % TSTEPS;
    const int m    = (idx / TSTEPS) & 15;
    const int tile = idx / (TSTEPS * 16);
    const float4 v = *(const float4*)(x + ((size_t)(tile * 16 + m) * TSTEPS + t) * 4);
    const s16x4 o = {(short)f2bf_rne(v.x), (short)f2bf_rne(v.y),
                     (short)f2bf_rne(v.z), (short)f2bf_rne(v.w)};
    *(s16x4*)(xf + ((size_t)(tile * TSTEPS + t) * 16 + m) * 4) = o;
}

// ---- L0 producer step: compute h0(K) from h0(K-1),x(K); publish; P=K&1 ----
// h0(s) at byte (s&1)<<11; h1(s) at 4096 + ((s&1)<<11).
#define L0STEP(K, P)                                                             \
  {                                                                              \
    bf16x8 ax;                                                                   \
    if (XPRE) { U8 u; u.p.lo = xv; u.p.hi = xv; ax = u.v8; }                     \
    else {                                                                       \
      ax = zfrag;                                                                \
      if (lg == 0) {                                                             \
        ax[0] = (short)f2bf_rne(xf4.x); ax[1] = (short)f2bf_rne(xf4.y);          \
        ax[2] = (short)f2bf_rne(xf4.z); ax[3] = (short)f2bf_rne(xf4.w);          \
      }                                                                          \
    }                                                                            \
    f32x4 acc0[4];                                                               \
    _Pragma("unroll") for (int G = 0; G < 4; ++G) {                              \
      acc0[G] = MFMA(A0[0], Bhh0[G][0], zero4);                                  \
      acc0[G] = MFMA(A0[1], Bhh0[G][1], acc0[G]);                                \
      acc0[G] = MFMA(ax,    Bih0[G],    acc0[G]);                                \
    }                                                                            \
    if ((K) + 1 < TSTEPS) {                                                      \
      if (XPRE) xv  = *(const s16x4*)(xfp + ((K) + 1) * 64);                     \
      else      xf4 = *(const float4*)(xb + ((K) + 1) * 4);                      \
    }                                                                            \
    _Pragma("unroll") for (int p = 0; p < 2; ++p) {                              \
      const f32x2 ig = sigv ((f32x2){acc0[0][2*p], acc0[0][2*p+1]} * nL2 + lb[0]); \
      const f32x2 fg = sigv ((f32x2){acc0[1][2*p], acc0[1][2*p+1]} * nL2 + lb[1]); \
      const f32x2 gg = tanhv((f32x2){acc0[2][2*p], acc0[2][2*p+1]} * L22 + lb[2]); \
      const f32x2 og = sigv ((f32x2){acc0[3][2*p], acc0[3][2*p+1]} * nL2 + lb[3]); \
      const f32x2 c  = fg * c0v[p] + ig * gg;                                    \
      c0v[p] = c;                                                                \
      const f32x2 h = og * tanhv(c * L22);                                       \
      *(unsigned short*)(HBc + ((P)<<11) + wbase + (2*p)  *16) = f2bf(h.x);      \
      *(unsigned short*)(HBc + ((P)<<11) + wbase + (2*p+1)*16) = f2bf(h.y);      \
    }                                                                            \
    bar_lds();                                                                   \
    A0[0] = *(const bf16x8*)(HBc + ((P)<<11) + rbase);                           \
    A0[1] = *(const bf16x8*)(HBc + ((P)<<11) + rbase + 1024);                    \
  }

// ---- L1 consumer step: compute h1(J) from h0(J),h1(J-1); publish; P=J&1 ----
// after barrier: h0(J+1) ready at buf0[P^1]; h1(J) at buf1[P].
#define L1STEP(J, P)                                                             \
  {                                                                              \
    f32x4 acc1[4];                                                               \
    _Pragma("unroll") for (int G = 0; G < 4; ++G) {                              \
      acc1[G] = MFMA(A0[0], Bih1[G][0], zero4);                                  \
      acc1[G] = MFMA(A0[1], Bih1[G][1], acc1[G]);                                \
      acc1[G] = MFMA(A1[0], Bhh1[G][0], acc1[G]);                                \
      acc1[G] = MFMA(A1[1], Bhh1[G][1], acc1[G]);                                \
    }                                                                            \
    _Pragma("unroll") for (int p = 0; p < 2; ++p) {                              \
      const f32x2 ig = sigv ((f32x2){acc1[0][2*p], acc1[0][2*p+1]} * nL2 + lb[0]); \
      const f32x2 fg = sigv ((f32x2){acc1[1][2*p], acc1[1][2*p+1]} * nL2 + lb[1]); \
      const f32x2 gg = tanhv((f32x2){acc1[2][2*p], acc1[2][2*p+1]} * L22 + lb[2]); \
      const f32x2 og = sigv ((f32x2){acc1[3][2*p], acc1[3][2*p+1]} * nL2 + lb[3]); \
      const f32x2 c  = fg * c1v[p] + ig * gg;                                    \
      c1v[p] = c;                                                                \
      const f32x2 h = og * tanhv(c * L22);                                       \
      *(unsigned short*)(HBc + 4096 + ((P)<<11) + wbase + (2*p)  *16) = f2bf(h.x); \
      *(unsigned short*)(HBc + 4096 + ((P)<<11) + wbase + (2*p+1)*16) = f2bf(h.y); \
    }                                                                            \
    bar_lds();                                                                   \
    A0[0] = *(const bf16x8*)(HBc + (((P)^1)<<11) + rbase);                       \
    A0[1] = *(const bf16x8*)(HBc + (((P)^1)<<11) + rbase + 1024);                \
    A1[0] = *(const bf16x8*)(HBc + 4096 + ((P)<<11) + rbase);                    \
    A1[1] = *(const bf16x8*)(HBc + 4096 + ((P)<<11) + rbase + 1024);             \
  }

// 8-wave blocks, layer-specialized: waves 0-3 run L0 only (48 weight regs),
// waves 4-7 run L1 only (64 weight regs). Per-wave total ~120 regs -> fits
// the (512,4) cap of 128 -> 4 waves/SIMD (2x round 9). Barrier counts match:
// L0 path 100+1, L1 path 1+99+1.
template<bool XPRE>
__global__ __launch_bounds__(512, 4) void lstm2_mfma(
    const float* __restrict__ x,
    const unsigned short* __restrict__ wsu, const float* __restrict__ wsf,
    const float* __restrict__ gam, const float* __restrict__ bet,
    const float* __restrict__ Wfc, const float* __restrict__ bfc,
    float* __restrict__ out)
{
    // Fragment-native h store (per 2KB buffer): element (m,k) at byte
    //   kc*1024 + ((k>>3)&3)*256 + m*16 + (k&7)*2
    // => A-frag read for lane l = bytes [l*16,l*16+16) (+1024 for kc=1):
    //    sequential across the wave, zero read conflicts.
    // buf0 p0/p1 @0/@2048 (h0), buf1 p0/p1 @4096/@6144 (h1).
    __shared__ __align__(16) unsigned short HB[4096];   // 8 KB
    __shared__ float H1F[BC * 65];   // f32 h1(T-1) for LN epilogue

    const int tid  = threadIdx.x;
    const int lane = tid & 63;
    const int wv   = __builtin_amdgcn_readfirstlane(tid >> 6); // 0..7
    const int ug   = wv & 3;           // unit-group within the layer
    const int ln15 = lane & 15, lg = lane >> 4;
    const int bblk = blockIdx.x * BC;

    // ---- t-invariant LDS byte addresses (within a 2KB buffer) ----
    const int kcw = ug >> 1;
    const int lgc = ((ug & 1) << 1) + (ln15 >> 3);
    const unsigned wbase = (unsigned)(kcw * 1024 + lgc * 256 + lg * 64 + (ln15 & 7) * 2);
    const unsigned rbase = (unsigned)(lane * 16);
    char* const HBc = (char*)HB;

    const f32x2 nL2 = {-LOG2E, -LOG2E};
    const f32x2 L22 = {2.0f * LOG2E, 2.0f * LOG2E};
    const f32x4 zero4 = {0.f, 0.f, 0.f, 0.f};
    const bf16x8 zfrag = {0,0,0,0,0,0,0,0};

    union U8 { bf16x8 v8; struct { s16x4 lo, hi; } p; };

    if (wv < 4) {
        // ================= L0 producer waves =================
        bf16x8 Bhh0[4][2], Bih0[4];
        #pragma unroll
        for (int G = 0; G < 4; ++G) {
            #pragma unroll
            for (int kc = 0; kc < 2; ++kc)
                Bhh0[G][kc] = *(const bf16x8*)(wsu + WS_WHH0_U + (((ug*4+G)*2+kc)*512 + lane*8));
            Bih0[G] = *(const bf16x8*)(wsu + WS_WIH0_U + (ug*4+G)*512 + lane*8);
        }
        f32x2 lb[4];
        #pragma unroll
        for (int G = 0; G < 4; ++G) {
            const float b0 = wsf[WS_B0_F + G * 64 + ug * 16 + ln15];
            const float s0 = (G == 2) ? (2.0f * LOG2E) * b0 : -LOG2E * b0;
            lb[G] = (f32x2){s0, s0};
        }
        f32x2 c0v[2] = {{0.f,0.f},{0.f,0.f}};
        bf16x8 A0[2]; A0[0] = zfrag; A0[1] = zfrag;   // h0(-1)=0

        const unsigned short* xfp = wsu + WS_XF_U + (size_t)blockIdx.x * (TSTEPS * 64) + ln15 * 4;
        const float* xb = x + (size_t)(bblk + ln15) * (TSTEPS * 4);
        s16x4 xv = {0,0,0,0};
        float4 xf4;
        if (XPRE) xv = *(const s16x4*)(xfp);       // lanes lg>0 replicate; their
        else      xf4 = *(const float4*)(xb);      // products hit zero B rows

        int k = 0;
        #pragma unroll 1
        for (int kb = 0; kb < TSTEPS / 2; ++kb) {  // 50 pairs: k=0..99, 100 bars
            L0STEP(k, 0);
            L0STEP(k + 1, 1);
            k += 2;
        }
        bar_lds();   // final: H1F ready

        if (tid < BC) {   // LN + FC (wave 0)
            const int b = tid;
            float hr[64];
            float mu = 0.f;
            #pragma unroll
            for (int q = 0; q < 64; ++q) { hr[q] = H1F[b * 65 + q]; mu += hr[q]; }
            mu *= (1.f / 64.f);
            float var = 0.f;
            #pragma unroll
            for (int q = 0; q < 64; ++q) { const float d = hr[q] - mu; var = fmaf(d, d, var); }
            var *= (1.f / 64.f);
            const float rs = rsqrtf(var + 1e-5f);
            float o0 = bfc[0], o1 = bfc[1];
            #pragma unroll
            for (int q = 0; q < 64; ++q) {
                const float nk = (hr[q] - mu) * rs * gam[q] + bet[q];
                o0 = fmaf(nk, Wfc[q],      o0);
                o1 = fmaf(nk, Wfc[64 + q], o1);
            }
            out[(size_t)(bblk + b) * 2 + 0] = o0;
            out[(size_t)(bblk + b) * 2 + 1] = o1;
        }
    } else {
        // ================= L1 consumer waves =================
        bf16x8 Bih1[4][2], Bhh1[4][2];
        #pragma unroll
        for (int G = 0; G < 4; ++G) {
            #pragma unroll
            for (int kc = 0; kc < 2; ++kc) {
                const int f = ((ug * 4 + G) * 2 + kc) * 512 + lane * 8;
                Bih1[G][kc] = *(const bf16x8*)(wsu + WS_WIH1_U + f);
                Bhh1[G][kc] = *(const bf16x8*)(wsu + WS_WHH1_U + f);
            }
        }
        f32x2 lb[4];
        #pragma unroll
        for (int G = 0; G < 4; ++G) {
            const float b1 = wsf[WS_B1_F + G * 64 + ug * 16 + ln15];
            const float s1 = (G == 2) ? (2.0f * LOG2E) * b1 : -LOG2E * b1;
            lb[G] = (f32x2){s1, s1};
        }
        f32x2 c1v[2] = {{0.f,0.f},{0.f,0.f}};
        bf16x8 A0[2], A1[2];
        A1[0] = zfrag; A1[1] = zfrag;   // h1(-1)=0

        bar_lds();   // bar #1: h0(0) published
        A0[0] = *(const bf16x8*)(HBc + rbase);          // buf0[0] = h0(0)
        A0[1] = *(const bf16x8*)(HBc + rbase + 1024);

        int j = 0;
        #pragma unroll 1
        for (int jb = 0; jb < (TSTEPS - 2) / 2; ++jb) {  // 49 pairs: j=0..97
            L1STEP(j, 0);
            L1STEP(j + 1, 1);
            j += 2;
        }
        L1STEP(98, 0);   // 99 loop bars total; A0=h0(99), A1=h1(98) now loaded

        // final step j=99 -> H1F (f32), then final barrier
        {
            f32x4 acc1[4];
            #pragma unroll
            for (int G = 0; G < 4; ++G) {
                acc1[G] = MFMA(A0[0], Bih1[G][0], zero4);
                acc1[G] = MFMA(A0[1], Bih1[G][1], acc1[G]);
                acc1[G] = MFMA(A1[0], Bhh1[G][0], acc1[G]);
                acc1[G] = MFMA(A1[1], Bhh1[G][1], acc1[G]);
            }
            #pragma unroll
            for (int p = 0; p < 2; ++p) {
                const f32x2 ig = sigv ((f32x2){acc1[0][2*p], acc1[0][2*p+1]} * nL2 + lb[0]);
                const f32x2 fg = sigv ((f32x2){acc1[1][2*p], acc1[1][2*p+1]} * nL2 + lb[1]);
                const f32x2 gg = tanhv((f32x2){acc1[2][2*p], acc1[2][2*p+1]} * L22 + lb[2]);
                const f32x2 og = sigv ((f32x2){acc1[3][2*p], acc1[3][2*p+1]} * nL2 + lb[3]);
                const f32x2 c  = fg * c1v[p] + ig * gg;
                c1v[p] = c;
                const f32x2 h = og * tanhv(c * L22);
                H1F[(lg * 4 + 2*p)     * 65 + ug * 16 + ln15] = h.x;
                H1F[(lg * 4 + 2*p + 1) * 65 + ug * 16 + ln15] = h.y;
            }
        }
        bar_lds();   // final
    }
}

extern "C" void kernel_launch(void* const* d_in, const int* in_sizes, int n_in,
                              void* d_out, int out_size, void* d_ws, size_t ws_size,
                              hipStream_t stream) {
    (void)in_sizes; (void)n_in; (void)out_size;
    const float* x    = (const float*)d_in[0];
    const float* Wih0 = (const float*)d_in[1];
    const float* Whh0 = (const float*)d_in[2];
    const float* bih0 = (const float*)d_in[3];
    const float* bhh0 = (const float*)d_in[4];
    const float* Wih1 = (const float*)d_in[5];
    const float* Whh1 = (const float*)d_in[6];
    const float* bih1 = (const float*)d_in[7];
    const float* bhh1 = (const float*)d_in[8];
    const float* gam  = (const float*)d_in[9];
    const float* bet  = (const float*)d_in[10];
    const float* Wfc  = (const float*)d_in[11];
    const float* bfc  = (const float*)d_in[12];
    unsigned short* wsu = (unsigned short*)d_ws;
    float*          wsf = (float*)d_ws;
    float* out = (float*)d_out;

    hipLaunchKernelGGL(reorder_w, dim3(96), dim3(256), 0, stream,
                       Wih0, Whh0, bih0, bhh0, Wih1, Whh1, bih1, bhh1, wsu, wsf);
    if (ws_size >= WS_NEED) {
        hipLaunchKernelGGL(prep_xfrag, dim3(NBLK * 16 * TSTEPS / 256), dim3(256), 0, stream,
                           x, wsu + WS_XF_U);
        hipLaunchKernelGGL((lstm2_mfma<true>), dim3(NBLK), dim3(512), 0, stream,
                           x, wsu, wsf, gam, bet, Wfc, bfc, out);
    } else {
        hipLaunchKernelGGL((lstm2_mfma<false>), dim3(NBLK), dim3(512), 0, stream,
                           x, wsu, wsf, gam, bet, Wfc, bfc, out);
    }
}

// Round 11
// 237.656 us; speedup vs baseline: 1.2494x; 1.1675x over previous
//
#include <hip/hip_runtime.h>

#define TSTEPS 100
#define BC     16
#define NBLK   (16384/BC)   // 1024 blocks

typedef __attribute__((ext_vector_type(8))) short bf16x8;
typedef __attribute__((ext_vector_type(4))) short s16x4;
typedef __attribute__((ext_vector_type(4))) float f32x4;
typedef __attribute__((ext_vector_type(2))) float f32x2;

// d_ws layout: ushort view for bf16 frags, float view for biases
#define WS_WHH0_U 0         // 16384 ushort
#define WS_WIH1_U 16384
#define WS_WHH1_U 32768
#define WS_WIH0_U 49152     // 8192 ushort -> ends at byte 114688
#define WS_B0_F   28672     // float idx (byte 114688)
#define WS_B1_F   28928     // ends at byte 116736
#define WS_XF_U   65536     // xfrag area, byte 131072; 1024*100*64 ushorts
#define WS_NEED   (131072 + (size_t)NBLK * TSTEPS * 64 * 2)

#define MFMA(A,B,C) __builtin_amdgcn_mfma_f32_16x16x32_bf16(A,B,C,0,0,0)
#define LOG2E 1.4426950408889634f

// RNE (one-shot formatting only)
__device__ __forceinline__ unsigned short f2bf_rne(float f) {
    unsigned int u = __float_as_uint(f);
    u += 0x7fffu + ((u >> 16) & 1u);
    return (unsigned short)(u >> 16);
}
// hot-loop: round-nearest-ties-up, 2 VALU ops
__device__ __forceinline__ unsigned short f2bf(float f) {
    return (unsigned short)((__float_as_uint(f) + 0x8000u) >> 16);
}
__device__ __forceinline__ f32x2 exp2v(f32x2 y) {
    return (f32x2){__builtin_amdgcn_exp2f(y.x), __builtin_amdgcn_exp2f(y.y)};
}
__device__ __forceinline__ f32x2 rcpv(f32x2 y) {
    return (f32x2){__builtin_amdgcn_rcpf(y.x), __builtin_amdgcn_rcpf(y.y)};
}

// Fused LSTM cell, rcp-merged. Inputs are PRESCALED gate args straight from
// MFMA (weights & bias carry the scale): yi,yf,yo = -L*(a+b); yg = 2L*(a+b).
//   i = 1/(1+Ei), f = 1/(1+Ef), g = (Eg-1)/(Eg+1), o = 1/(1+Eo)
//   c' = f*c + i*g = [c*(1+Ei)(Eg+1) + (Eg-1)(1+Ef)] * rcp((1+Ei)(1+Ef)(Eg+1))
//   h  = o*tanh(2L*c') = (Ec-1) * rcp((1+Eo)(Ec+1)),  Ec = 2^(2L*c')
// 10 exp2 + 4 rcp per pair (was 10 exp2 + 10 rcp). All rcp args >= 1.
__device__ __forceinline__ f32x2 lstm_cell(f32x2 yi, f32x2 yf, f32x2 yg, f32x2 yo,
                                           f32x2& c) {
    const f32x2 one = {1.f, 1.f};
    const f32x2 L22 = {2.0f * LOG2E, 2.0f * LOG2E};
    const f32x2 Ei = exp2v(yi), Ef = exp2v(yf), Eg = exp2v(yg), Eo = exp2v(yo);
    const f32x2 t1 = Ei + one, t2 = Ef + one, t3 = Eg + one, t4 = Eg - one;
    const f32x2 u  = t1 * t3;
    const f32x2 R1 = rcpv(u * t2);
    c = (c * u + t4 * t2) * R1;
    const f32x2 Ec = exp2v(c * L22);
    const f32x2 t5 = Ec - one, t6 = Ec + one, t7 = Eo + one;
    const f32x2 R2 = rcpv(t7 * t6);
    return t5 * R2;
}

// lgkm-only barrier: keeps global prefetch (vmcnt) in flight across the sync
__device__ __forceinline__ void bar_lds() {
    asm volatile("s_waitcnt lgkmcnt(0)\n\ts_barrier" ::: "memory");
}

// One-shot: weights into per-lane MFMA B-frag order (bf16), PRESCALED by the
// activation constants (-L for i,f,o rows; 2L for g rows); biases likewise.
// Frag (ug,G,kc): lane l, elem j <-> W[row=G*64+ug*16+(l&15)][k=kc*32+(l>>4)*8+j]
__global__ void reorder_w(const float* __restrict__ Wih0, const float* __restrict__ Whh0,
                          const float* __restrict__ bih0, const float* __restrict__ bhh0,
                          const float* __restrict__ Wih1, const float* __restrict__ Whh1,
                          const float* __restrict__ bih1, const float* __restrict__ bhh1,
                          unsigned short* __restrict__ wsu, float* __restrict__ wsf)
{
    const int idx = blockIdx.x * 256 + threadIdx.x;   // 0..24575
    if (idx < 16384) {
        const int j = idx & 7, lane = (idx >> 3) & 63, kc = (idx >> 9) & 1,
                  G = (idx >> 10) & 3, ug = (idx >> 12) & 3;
        const int row = G * 64 + ug * 16 + (lane & 15);
        const int k   = kc * 32 + (lane >> 4) * 8 + j;
        const float sc = (G == 2) ? (2.0f * LOG2E) : -LOG2E;
        wsu[WS_WHH0_U + idx] = f2bf_rne(sc * Whh0[row * 64 + k]);
        wsu[WS_WIH1_U + idx] = f2bf_rne(sc * Wih1[row * 64 + k]);
        wsu[WS_WHH1_U + idx] = f2bf_rne(sc * Whh1[row * 64 + k]);
    }
    if (idx < 8192) {
        const int j = idx & 7, lane = (idx >> 3) & 63, G = (idx >> 9) & 3, ug = (idx >> 11) & 3;
        const int row = G * 64 + ug * 16 + (lane & 15);
        const float sc = (G == 2) ? (2.0f * LOG2E) : -LOG2E;
        // rows k>=4 are EXACT zeros -> main kernel may feed garbage A there
        const float v = ((lane >> 4) == 0 && j < 4) ? sc * Wih0[row * 4 + j] : 0.0f;
        wsu[WS_WIH0_U + idx] = f2bf_rne(v);
    }
    if (idx < 256) {
        const int G = idx >> 6;
        const float sc = (G == 2) ? (2.0f * LOG2E) : -LOG2E;
        wsf[WS_B0_F + idx] = sc * (bih0[idx] + bhh0[idx]);
        wsf[WS_B1_F + idx] = sc * (bih1[idx] + bhh1[idx]);
    }
}

// One-shot: x -> bf16 in A-frag-ready order. [tile][t][m 0..15][4 bf16]
__global__ void prep_xfrag(const float* __restrict__ x, unsigned short* __restrict__ xf) {
    const int idx = blockIdx.x * 256 + threadIdx.x;      // tile*1600 + m*100 + t
    const int t    = idx % TSTEPS;
    const int m    = (idx / TSTEPS) & 15;
    const int tile = idx / (TSTEPS * 16);
    const float4 v = *(const float4*)(x + ((size_t)(tile * 16 + m) * TSTEPS + t) * 4);
    const s16x4 o = {(short)f2bf_rne(v.x), (short)f2bf_rne(v.y),
                     (short)f2bf_rne(v.z), (short)f2bf_rne(v.w)};
    *(s16x4*)(xf + ((size_t)(tile * TSTEPS + t) * 16 + m) * 4) = o;
}

// ---- L0 producer step: compute h0(K) from h0(K-1),x(K); publish; P=K&1 ----
#define L0STEP(K, P)                                                             \
  {                                                                              \
    bf16x8 ax;                                                                   \
    if (XPRE) { U8 u_; u_.p.lo = xv; u_.p.hi = xv; ax = u_.v8; }                 \
    else {                                                                       \
      ax = zfrag;                                                                \
      if (lg == 0) {                                                             \
        ax[0] = (short)f2bf_rne(xf4.x); ax[1] = (short)f2bf_rne(xf4.y);          \
        ax[2] = (short)f2bf_rne(xf4.z); ax[3] = (short)f2bf_rne(xf4.w);          \
      }                                                                          \
    }                                                                            \
    f32x4 acc0[4];                                                               \
    _Pragma("unroll") for (int G = 0; G < 4; ++G) {                              \
      acc0[G] = MFMA(A0[0], Bhh0[G][0], bV[G]);                                  \
      acc0[G] = MFMA(A0[1], Bhh0[G][1], acc0[G]);                                \
      acc0[G] = MFMA(ax,    Bih0[G],    acc0[G]);                                \
    }                                                                            \
    if ((K) + 1 < TSTEPS) {                                                      \
      if (XPRE) xv  = *(const s16x4*)(xfp + ((K) + 1) * 64);                     \
      else      xf4 = *(const float4*)(xb + ((K) + 1) * 4);                      \
    }                                                                            \
    _Pragma("unroll") for (int p = 0; p < 2; ++p) {                              \
      const f32x2 h = lstm_cell(                                                 \
        (f32x2){acc0[0][2*p], acc0[0][2*p+1]},                                   \
        (f32x2){acc0[1][2*p], acc0[1][2*p+1]},                                   \
        (f32x2){acc0[2][2*p], acc0[2][2*p+1]},                                   \
        (f32x2){acc0[3][2*p], acc0[3][2*p+1]}, c0v[p]);                          \
      *(unsigned short*)(HBc + ((P)<<11) + wbase + (2*p)  *16) = f2bf(h.x);      \
      *(unsigned short*)(HBc + ((P)<<11) + wbase + (2*p+1)*16) = f2bf(h.y);      \
    }                                                                            \
    bar_lds();                                                                   \
    A0[0] = *(const bf16x8*)(HBc + ((P)<<11) + rbase);                           \
    A0[1] = *(const bf16x8*)(HBc + ((P)<<11) + rbase + 1024);                    \
  }

// ---- L1 consumer step: compute h1(J) from h0(J),h1(J-1); publish; P=J&1 ----
#define L1STEP(J, P)                                                             \
  {                                                                              \
    f32x4 acc1[4];                                                               \
    _Pragma("unroll") for (int G = 0; G < 4; ++G) {                              \
      acc1[G] = MFMA(A0[0], Bih1[G][0], bV[G]);                                  \
      acc1[G] = MFMA(A0[1], Bih1[G][1], acc1[G]);                                \
      acc1[G] = MFMA(A1[0], Bhh1[G][0], acc1[G]);                                \
      acc1[G] = MFMA(A1[1], Bhh1[G][1], acc1[G]);                                \
    }                                                                            \
    _Pragma("unroll") for (int p = 0; p < 2; ++p) {                              \
      const f32x2 h = lstm_cell(                                                 \
        (f32x2){acc1[0][2*p], acc1[0][2*p+1]},                                   \
        (f32x2){acc1[1][2*p], acc1[1][2*p+1]},                                   \
        (f32x2){acc1[2][2*p], acc1[2][2*p+1]},                                   \
        (f32x2){acc1[3][2*p], acc1[3][2*p+1]}, c1v[p]);                          \
      *(unsigned short*)(HBc + 4096 + ((P)<<11) + wbase + (2*p)  *16) = f2bf(h.x); \
      *(unsigned short*)(HBc + 4096 + ((P)<<11) + wbase + (2*p+1)*16) = f2bf(h.y); \
    }                                                                            \
    bar_lds();                                                                   \
    A0[0] = *(const bf16x8*)(HBc + (((P)^1)<<11) + rbase);                       \
    A0[1] = *(const bf16x8*)(HBc + (((P)^1)<<11) + rbase + 1024);                \
    A1[0] = *(const bf16x8*)(HBc + 4096 + ((P)<<11) + rbase);                    \
    A1[1] = *(const bf16x8*)(HBc + 4096 + ((P)<<11) + rbase + 1024);             \
  }

// 8-wave blocks, layer-specialized (waves 0-3: L0; 4-7: L1).
// (512,3): reg cap ~170 -> room for +16 bias VGPRs without spill
// (round-5 lesson: too-tight cap -> 4GB scratch traffic; tripwire FETCH_SIZE).
template<bool XPRE>
__global__ __launch_bounds__(512, 3) void lstm2_mfma(
    const float* __restrict__ x,
    const unsigned short* __restrict__ wsu, const float* __restrict__ wsf,
    const float* __restrict__ gam, const float* __restrict__ bet,
    const float* __restrict__ Wfc, const float* __restrict__ bfc,
    float* __restrict__ out)
{
    // Fragment-native h store (per 2KB buffer): element (m,k) at byte
    //   kc*1024 + ((k>>3)&3)*256 + m*16 + (k&7)*2
    // => A-frag read for lane l = bytes [l*16,l*16+16) (+1024 for kc=1):
    //    sequential across the wave, zero read conflicts.
    // buf0 p0/p1 @0/@2048 (h0), buf1 p0/p1 @4096/@6144 (h1).
    __shared__ __align__(16) unsigned short HB[4096];   // 8 KB
    __shared__ float H1F[BC * 65];   // f32 h1(T-1) for LN epilogue

    const int tid  = threadIdx.x;
    const int lane = tid & 63;
    const int wv   = __builtin_amdgcn_readfirstlane(tid >> 6); // 0..7
    const int ug   = wv & 3;           // unit-group within the layer
    const int ln15 = lane & 15, lg = lane >> 4;
    const int bblk = blockIdx.x * BC;

    // ---- t-invariant LDS byte addresses (within a 2KB buffer) ----
    const int kcw = ug >> 1;
    const int lgc = ((ug & 1) << 1) + (ln15 >> 3);
    const unsigned wbase = (unsigned)(kcw * 1024 + lgc * 256 + lg * 64 + (ln15 & 7) * 2);
    const unsigned rbase = (unsigned)(lane * 16);
    char* const HBc = (char*)HB;

    const bf16x8 zfrag = {0,0,0,0,0,0,0,0};
    union U8 { bf16x8 v8; struct { s16x4 lo, hi; } p; };

    if (wv < 4) {
        // ================= L0 producer waves =================
        bf16x8 Bhh0[4][2], Bih0[4];
        #pragma unroll
        for (int G = 0; G < 4; ++G) {
            #pragma unroll
            for (int kc = 0; kc < 2; ++kc)
                Bhh0[G][kc] = *(const bf16x8*)(wsu + WS_WHH0_U + (((ug*4+G)*2+kc)*512 + lane*8));
            Bih0[G] = *(const bf16x8*)(wsu + WS_WIH0_U + (ug*4+G)*512 + lane*8);
        }
        // prescaled bias as MFMA C-operand broadcast (acc rows = batch, same unit)
        f32x4 bV[4];
        #pragma unroll
        for (int G = 0; G < 4; ++G) {
            const float b = wsf[WS_B0_F + G * 64 + ug * 16 + ln15];
            bV[G] = (f32x4){b, b, b, b};
        }
        f32x2 c0v[2] = {{0.f,0.f},{0.f,0.f}};
        bf16x8 A0[2]; A0[0] = zfrag; A0[1] = zfrag;   // h0(-1)=0

        const unsigned short* xfp = wsu + WS_XF_U + (size_t)blockIdx.x * (TSTEPS * 64) + ln15 * 4;
        const float* xb = x + (size_t)(bblk + ln15) * (TSTEPS * 4);
        s16x4 xv = {0,0,0,0};
        float4 xf4;
        if (XPRE) xv = *(const s16x4*)(xfp);       // lanes lg>0 replicate; their
        else      xf4 = *(const float4*)(xb);      // products hit zero B rows

        int k = 0;
        #pragma unroll 1
        for (int kb = 0; kb < TSTEPS / 2; ++kb) {  // 50 pairs: k=0..99, 100 bars
            L0STEP(k, 0);
            L0STEP(k + 1, 1);
            k += 2;
        }
        bar_lds();   // final: H1F ready

        if (tid < BC) {   // LN + FC (wave 0)
            const int b = tid;
            float hr[64];
            float mu = 0.f;
            #pragma unroll
            for (int q = 0; q < 64; ++q) { hr[q] = H1F[b * 65 + q]; mu += hr[q]; }
            mu *= (1.f / 64.f);
            float var = 0.f;
            #pragma unroll
            for (int q = 0; q < 64; ++q) { const float d = hr[q] - mu; var = fmaf(d, d, var); }
            var *= (1.f / 64.f);
            const float rs = rsqrtf(var + 1e-5f);
            float o0 = bfc[0], o1 = bfc[1];
            #pragma unroll
            for (int q = 0; q < 64; ++q) {
                const float nk = (hr[q] - mu) * rs * gam[q] + bet[q];
                o0 = fmaf(nk, Wfc[q],      o0);
                o1 = fmaf(nk, Wfc[64 + q], o1);
            }
            out[(size_t)(bblk + b) * 2 + 0] = o0;
            out[(size_t)(bblk + b) * 2 + 1] = o1;
        }
    } else {
        // ================= L1 consumer waves =================
        bf16x8 Bih1[4][2], Bhh1[4][2];
        #pragma unroll
        for (int G = 0; G < 4; ++G) {
            #pragma unroll
            for (int kc = 0; kc < 2; ++kc) {
                const int f = ((ug * 4 + G) * 2 + kc) * 512 + lane * 8;
                Bih1[G][kc] = *(const bf16x8*)(wsu + WS_WIH1_U + f);
                Bhh1[G][kc] = *(const bf16x8*)(wsu + WS_WHH1_U + f);
            }
        }
        f32x4 bV[4];
        #pragma unroll
        for (int G = 0; G < 4; ++G) {
            const float b = wsf[WS_B1_F + G * 64 + ug * 16 + ln15];
            bV[G] = (f32x4){b, b, b, b};
        }
        f32x2 c1v[2] = {{0.f,0.f},{0.f,0.f}};
        bf16x8 A0[2], A1[2];
        A1[0] = zfrag; A1[1] = zfrag;   // h1(-1)=0

        bar_lds();   // bar #1: h0(0) published
        A0[0] = *(const bf16x8*)(HBc + rbase);          // buf0[0] = h0(0)
        A0[1] = *(const bf16x8*)(HBc + rbase + 1024);

        int j = 0;
        #pragma unroll 1
        for (int jb = 0; jb < (TSTEPS - 2) / 2; ++jb) {  // 49 pairs: j=0..97
            L1STEP(j, 0);
            L1STEP(j + 1, 1);
            j += 2;
        }
        L1STEP(98, 0);   // 99 loop bars total; A0=h0(99), A1=h1(98) now loaded

        // final step j=99 -> H1F (f32), then final barrier
        {
            f32x4 acc1[4];
            #pragma unroll
            for (int G = 0; G < 4; ++G) {
                acc1[G] = MFMA(A0[0], Bih1[G][0], bV[G]);
                acc1[G] = MFMA(A0[1], Bih1[G][1], acc1[G]);
                acc1[G] = MFMA(A1[0], Bhh1[G][0], acc1[G]);
                acc1[G] = MFMA(A1[1], Bhh1[G][1], acc1[G]);
            }
            #pragma unroll
            for (int p = 0; p < 2; ++p) {
                const f32x2 h = lstm_cell(
                    (f32x2){acc1[0][2*p], acc1[0][2*p+1]},
                    (f32x2){acc1[1][2*p], acc1[1][2*p+1]},
                    (f32x2){acc1[2][2*p], acc1[2][2*p+1]},
                    (f32x2){acc1[3][2*p], acc1[3][2*p+1]}, c1v[p]);
                H1F[(lg * 4 + 2*p)     * 65 + ug * 16 + ln15] = h.x;
                H1F[(lg * 4 + 2*p + 1) * 65 + ug * 16 + ln15] = h.y;
            }
        }
        bar_lds();   // final
    }
}

extern "C" void kernel_launch(void* const* d_in, const int* in_sizes, int n_in,
                              void* d_out, int out_size, void* d_ws, size_t ws_size,
                              hipStream_t stream) {
    (void)in_sizes; (void)n_in; (void)out_size;
    const float* x    = (const float*)d_in[0];
    const float* Wih0 = (const float*)d_in[1];
    const float* Whh0 = (const float*)d_in[2];
    const float* bih0 = (const float*)d_in[3];
    const float* bhh0 = (const float*)d_in[4];
    const float* Wih1 = (const float*)d_in[5];
    const float* Whh1 = (const float*)d_in[6];
    const float* bih1 = (const float*)d_in[7];
    const float* bhh1 = (const float*)d_in[8];
    const float* gam  = (const float*)d_in[9];
    const float* bet  = (const float*)d_in[10];
    const float* Wfc  = (const float*)d_in[11];
    const float* bfc  = (const float*)d_in[12];
    unsigned short* wsu = (unsigned short*)d_ws;
    float*          wsf = (float*)d_ws;
    float* out = (float*)d_out;

    hipLaunchKernelGGL(reorder_w, dim3(96), dim3(256), 0, stream,
                       Wih0, Whh0, bih0, bhh0, Wih1, Whh1, bih1, bhh1, wsu, wsf);
    if (ws_size >= WS_NEED) {
        hipLaunchKernelGGL(prep_xfrag, dim3(NBLK * 16 * TSTEPS / 256), dim3(256), 0, stream,
                           x, wsu + WS_XF_U);
        hipLaunchKernelGGL((lstm2_mfma<true>), dim3(NBLK), dim3(512), 0, stream,
                           x, wsu, wsf, gam, bet, Wfc, bfc, out);
    } else {
        hipLaunchKernelGGL((lstm2_mfma<false>), dim3(NBLK), dim3(512), 0, stream,
                           x, wsu, wsf, gam, bet, Wfc, bfc, out);
    }
}

// Round 12
// 224.847 us; speedup vs baseline: 1.3205x; 1.0570x over previous
//
#include <hip/hip_runtime.h>

#define TSTEPS 100
#define BC     16
#define NBLK   (16384/BC)   // 1024 blocks

typedef __attribute__((ext_vector_type(8))) short bf16x8;
typedef __attribute__((ext_vector_type(4))) short s16x4;
typedef __attribute__((ext_vector_type(4))) float f32x4;
typedef __attribute__((ext_vector_type(2))) float f32x2;

// d_ws layout: ushort view for bf16 frags, float view for biases
#define WS_WHH0_U 0         // 16384 ushort
#define WS_WIH1_U 16384
#define WS_WHH1_U 32768
#define WS_WIH0_U 49152     // 8192 ushort -> ends at byte 114688
#define WS_B0_F   28672     // float idx (byte 114688)
#define WS_B1_F   28928     // ends at byte 116736
#define WS_XF_U   65536     // xfrag area, byte 131072; 1024*100*64 ushorts
#define WS_NEED   (131072 + (size_t)NBLK * TSTEPS * 64 * 2)

#define MFMA(A,B,C) __builtin_amdgcn_mfma_f32_16x16x32_bf16(A,B,C,0,0,0)
#define LOG2E 1.4426950408889634f

// RNE (one-shot formatting only)
__device__ __forceinline__ unsigned short f2bf_rne(float f) {
    unsigned int u = __float_as_uint(f);
    u += 0x7fffu + ((u >> 16) & 1u);
    return (unsigned short)(u >> 16);
}
// hot-loop: round-nearest-ties-up, 2 VALU ops
__device__ __forceinline__ unsigned short f2bf(float f) {
    return (unsigned short)((__float_as_uint(f) + 0x8000u) >> 16);
}
__device__ __forceinline__ f32x2 exp2v(f32x2 y) {
    return (f32x2){__builtin_amdgcn_exp2f(y.x), __builtin_amdgcn_exp2f(y.y)};
}
__device__ __forceinline__ f32x2 rcpv(f32x2 y) {
    return (f32x2){__builtin_amdgcn_rcpf(y.x), __builtin_amdgcn_rcpf(y.y)};
}

// Fused LSTM cell, rcp-merged + fma-packed. Inputs are PRESCALED gate args
// straight from MFMA (weights & bias carry the scale):
//   yi,yf,yo = -L*(a+b); yg = 2L*(a+b)
//   i=1/(1+Ei), f=1/(1+Ef), g=(Eg-1)/(Eg+1), o=1/(1+Eo)
//   c' = [c*(1+Ei)(Eg+1) + (Eg-1)(1+Ef)] * rcp((1+Ei)(1+Ef)(Eg+1))
//   h  = (Ec-1) * rcp((1+Eo)(Ec+1)),  Ec = 2^(2L*c')
// 10 exp2 + 4 rcp + 11 pk-alg per pair. All rcp args >= 1; max magnitude
// ~2^50 (|gate arg| <= ~12) -- no overflow.
__device__ __forceinline__ f32x2 lstm_cell(f32x2 yi, f32x2 yf, f32x2 yg, f32x2 yo,
                                           f32x2& c) {
    const f32x2 one = {1.f, 1.f};
    const f32x2 L22 = {2.0f * LOG2E, 2.0f * LOG2E};
    const f32x2 Ei = exp2v(yi), Ef = exp2v(yf), Eg = exp2v(yg), Eo = exp2v(yo);
    const f32x2 t2 = Ef + one;
    const f32x2 t3 = Eg + one;
    const f32x2 u  = Ei * t3 + t3;        // (1+Ei)(1+Eg)   -> pk_fma
    const f32x2 n  = Eg * t2 - t2;        // (Eg-1)(1+Ef)   -> pk_fma
    const f32x2 R1 = rcpv(u * t2);
    c = (c * u + n) * R1;                 // pk_fma + pk_mul
    const f32x2 Ec = exp2v(c * L22);
    const f32x2 t6 = Ec + one;
    const f32x2 R2 = rcpv(Eo * t6 + t6);  // (1+Eo)(1+Ec)   -> pk_fma
    return Ec * R2 - R2;                  // (Ec-1)*R2      -> pk_fma
}

// lgkm-only barrier: keeps global prefetch (vmcnt) in flight across the sync
__device__ __forceinline__ void bar_lds() {
    asm volatile("s_waitcnt lgkmcnt(0)\n\ts_barrier" ::: "memory");
}

// One-shot: weights into per-lane MFMA B-frag order (bf16), PRESCALED by the
// activation constants (-L for i,f,o rows; 2L for g rows); biases likewise.
// Frag (ug,G,kc): lane l, elem j <-> W[row=G*64+ug*16+(l&15)][k=kc*32+(l>>4)*8+j]
__global__ void reorder_w(const float* __restrict__ Wih0, const float* __restrict__ Whh0,
                          const float* __restrict__ bih0, const float* __restrict__ bhh0,
                          const float* __restrict__ Wih1, const float* __restrict__ Whh1,
                          const float* __restrict__ bih1, const float* __restrict__ bhh1,
                          unsigned short* __restrict__ wsu, float* __restrict__ wsf)
{
    const int idx = blockIdx.x * 256 + threadIdx.x;   // 0..24575
    if (idx < 16384) {
        const int j = idx & 7, lane = (idx >> 3) & 63, kc = (idx >> 9) & 1,
                  G = (idx >> 10) & 3, ug = (idx >> 12) & 3;
        const int row = G * 64 + ug * 16 + (lane & 15);
        const int k   = kc * 32 + (lane >> 4) * 8 + j;
        const float sc = (G == 2) ? (2.0f * LOG2E) : -LOG2E;
        wsu[WS_WHH0_U + idx] = f2bf_rne(sc * Whh0[row * 64 + k]);
        wsu[WS_WIH1_U + idx] = f2bf_rne(sc * Wih1[row * 64 + k]);
        wsu[WS_WHH1_U + idx] = f2bf_rne(sc * Whh1[row * 64 + k]);
    }
    if (idx < 8192) {
        const int j = idx & 7, lane = (idx >> 3) & 63, G = (idx >> 9) & 3, ug = (idx >> 11) & 3;
        const int row = G * 64 + ug * 16 + (lane & 15);
        const float sc = (G == 2) ? (2.0f * LOG2E) : -LOG2E;
        // rows k>=4 are EXACT zeros -> main kernel may feed garbage A there
        const float v = ((lane >> 4) == 0 && j < 4) ? sc * Wih0[row * 4 + j] : 0.0f;
        wsu[WS_WIH0_U + idx] = f2bf_rne(v);
    }
    if (idx < 256) {
        const int G = idx >> 6;
        const float sc = (G == 2) ? (2.0f * LOG2E) : -LOG2E;
        wsf[WS_B0_F + idx] = sc * (bih0[idx] + bhh0[idx]);
        wsf[WS_B1_F + idx] = sc * (bih1[idx] + bhh1[idx]);
    }
}

// One-shot: x -> bf16 in A-frag-ready order. [tile][t][m 0..15][4 bf16]
__global__ void prep_xfrag(const float* __restrict__ x, unsigned short* __restrict__ xf) {
    const int idx = blockIdx.x * 256 + threadIdx.x;      // tile*1600 + m*100 + t
    const int t    = idx % TSTEPS;
    const int m    = (idx / TSTEPS) & 15;
    const int tile = idx / (TSTEPS * 16);
    const float4 v = *(const float4*)(x + ((size_t)(tile * 16 + m) * TSTEPS + t) * 4);
    const s16x4 o = {(short)f2bf_rne(v.x), (short)f2bf_rne(v.y),
                     (short)f2bf_rne(v.z), (short)f2bf_rne(v.w)};
    *(s16x4*)(xf + ((size_t)(tile * TSTEPS + t) * 16 + m) * 4) = o;
}

// ---- L0 producer step: compute h0(K) from h0(K-1),x(K); publish; P=K&1 ----
#define L0STEP(K, P)                                                             \
  {                                                                              \
    bf16x8 ax;                                                                   \
    if (XPRE) { U8 u_; u_.p.lo = xv; u_.p.hi = xv; ax = u_.v8; }                 \
    else {                                                                       \
      ax = zfrag;                                                                \
      if (lg == 0) {                                                             \
        ax[0] = (short)f2bf_rne(xf4.x); ax[1] = (short)f2bf_rne(xf4.y);          \
        ax[2] = (short)f2bf_rne(xf4.z); ax[3] = (short)f2bf_rne(xf4.w);          \
      }                                                                          \
    }                                                                            \
    f32x4 acc0[4];                                                               \
    _Pragma("unroll") for (int G = 0; G < 4; ++G) {                              \
      acc0[G] = MFMA(A0[0], Bhh0[G][0], bV[G]);                                  \
      acc0[G] = MFMA(A0[1], Bhh0[G][1], acc0[G]);                                \
      acc0[G] = MFMA(ax,    Bih0[G],    acc0[G]);                                \
    }                                                                            \
    if ((K) + 1 < TSTEPS) {                                                      \
      if (XPRE) xv  = *(const s16x4*)(xfp + ((K) + 1) * 64);                     \
      else      xf4 = *(const float4*)(xb + ((K) + 1) * 4);                      \
    }                                                                            \
    _Pragma("unroll") for (int p = 0; p < 2; ++p) {                              \
      const f32x2 h = lstm_cell(                                                 \
        (f32x2){acc0[0][2*p], acc0[0][2*p+1]},                                   \
        (f32x2){acc0[1][2*p], acc0[1][2*p+1]},                                   \
        (f32x2){acc0[2][2*p], acc0[2][2*p+1]},                                   \
        (f32x2){acc0[3][2*p], acc0[3][2*p+1]}, c0v[p]);                          \
      *(unsigned short*)(HBc + ((P)<<11) + wadr[2*p])   = f2bf(h.x);             \
      *(unsigned short*)(HBc + ((P)<<11) + wadr[2*p+1]) = f2bf(h.y);             \
    }                                                                            \
    bar_lds();                                                                   \
    A0[0] = *(const bf16x8*)(HBc + ((P)<<11) + rbase);                           \
    A0[1] = *(const bf16x8*)(HBc + ((P)<<11) + rbase + 1024);                    \
  }

// ---- L1 consumer step: compute h1(J) from h0(J),h1(J-1); publish; P=J&1 ----
#define L1STEP(J, P)                                                             \
  {                                                                              \
    f32x4 acc1[4];                                                               \
    _Pragma("unroll") for (int G = 0; G < 4; ++G) {                              \
      acc1[G] = MFMA(A0[0], Bih1[G][0], bV[G]);                                  \
      acc1[G] = MFMA(A0[1], Bih1[G][1], acc1[G]);                                \
      acc1[G] = MFMA(A1[0], Bhh1[G][0], acc1[G]);                                \
      acc1[G] = MFMA(A1[1], Bhh1[G][1], acc1[G]);                                \
    }                                                                            \
    _Pragma("unroll") for (int p = 0; p < 2; ++p) {                              \
      const f32x2 h = lstm_cell(                                                 \
        (f32x2){acc1[0][2*p], acc1[0][2*p+1]},                                   \
        (f32x2){acc1[1][2*p], acc1[1][2*p+1]},                                   \
        (f32x2){acc1[2][2*p], acc1[2][2*p+1]},                                   \
        (f32x2){acc1[3][2*p], acc1[3][2*p+1]}, c1v[p]);                          \
      *(unsigned short*)(HBc + 4096 + ((P)<<11) + wadr[2*p])   = f2bf(h.x);      \
      *(unsigned short*)(HBc + 4096 + ((P)<<11) + wadr[2*p+1]) = f2bf(h.y);      \
    }                                                                            \
    bar_lds();                                                                   \
    A0[0] = *(const bf16x8*)(HBc + (((P)^1)<<11) + rbase);                       \
    A0[1] = *(const bf16x8*)(HBc + (((P)^1)<<11) + rbase + 1024);                \
    A1[0] = *(const bf16x8*)(HBc + 4096 + ((P)<<11) + rbase);                    \
    A1[1] = *(const bf16x8*)(HBc + 4096 + ((P)<<11) + rbase + 1024);             \
  }

// 8-wave blocks, layer-specialized (waves 0-3: L0; 4-7: L1).
// (512,3): reg cap ~170 -> headroom, no spill (round-5 lesson; tripwire FETCH).
template<bool XPRE>
__global__ __launch_bounds__(512, 3) void lstm2_mfma(
    const float* __restrict__ x,
    const unsigned short* __restrict__ wsu, const float* __restrict__ wsf,
    const float* __restrict__ gam, const float* __restrict__ bet,
    const float* __restrict__ Wfc, const float* __restrict__ bfc,
    float* __restrict__ out)
{
    // Fragment-native h store (per 2KB buffer): element (m,k) at byte
    //   [kc*1024 + ((k>>3)&3)*256 + m*16 + (k&7)*2] ^ SWZ, where
    //   SWZ = (bit7<<4)|(bit8<<5) of the unswizzled address.
    // Reads (lane*16 ^ rswz): 16B-granular permutation of a contiguous
    // block -> conflict-free. Writes: banks spread over all 32 (was ~8-way
    // on banks {0-3,16-19} -> 6.5M conflict cycles in rounds 7-11).
    // buf0 p0/p1 @0/@2048 (h0), buf1 p0/p1 @4096/@6144 (h1).
    __shared__ __align__(16) unsigned short HB[4096];   // 8 KB
    __shared__ float H1F[BC * 65];   // f32 h1(T-1) for LN epilogue

    const int tid  = threadIdx.x;
    const int lane = tid & 63;
    const int wv   = __builtin_amdgcn_readfirstlane(tid >> 6); // 0..7
    const int ug   = wv & 3;           // unit-group within the layer
    const int ln15 = lane & 15, lg = lane >> 4;
    const int bblk = blockIdx.x * BC;

    // ---- t-invariant swizzled LDS byte addresses (within a 2KB buffer) ----
    // write addr bits: bit7 = lg>>1 (r*16 never carries), bit8 = ln15>>3
    const int kcw = ug >> 1;
    const int lgc = ((ug & 1) << 1) + (ln15 >> 3);
    const unsigned wswz = (unsigned)((((lg >> 1) & 1) << 4) | (((ln15 >> 3) & 1) << 5));
    unsigned wadr[4];
    #pragma unroll
    for (int r = 0; r < 4; ++r)
        wadr[r] = ((unsigned)(kcw * 1024 + lgc * 256 + lg * 64 + r * 16 + (ln15 & 7) * 2)) ^ wswz;
    // read addr bits: bit7 = lane>>3 &1, bit8 = lane>>4 &1 (of lane*16)
    const unsigned rswz = (unsigned)((((lane >> 3) & 1) << 4) | (((lane >> 4) & 1) << 5));
    const unsigned rbase = ((unsigned)(lane * 16)) ^ rswz;
    char* const HBc = (char*)HB;

    const bf16x8 zfrag = {0,0,0,0,0,0,0,0};
    union U8 { bf16x8 v8; struct { s16x4 lo, hi; } p; };

    if (wv < 4) {
        // ================= L0 producer waves =================
        bf16x8 Bhh0[4][2], Bih0[4];
        #pragma unroll
        for (int G = 0; G < 4; ++G) {
            #pragma unroll
            for (int kc = 0; kc < 2; ++kc)
                Bhh0[G][kc] = *(const bf16x8*)(wsu + WS_WHH0_U + (((ug*4+G)*2+kc)*512 + lane*8));
            Bih0[G] = *(const bf16x8*)(wsu + WS_WIH0_U + (ug*4+G)*512 + lane*8);
        }
        // prescaled bias as MFMA C-operand broadcast
        f32x4 bV[4];
        #pragma unroll
        for (int G = 0; G < 4; ++G) {
            const float b = wsf[WS_B0_F + G * 64 + ug * 16 + ln15];
            bV[G] = (f32x4){b, b, b, b};
        }
        f32x2 c0v[2] = {{0.f,0.f},{0.f,0.f}};
        bf16x8 A0[2]; A0[0] = zfrag; A0[1] = zfrag;   // h0(-1)=0

        const unsigned short* xfp = wsu + WS_XF_U + (size_t)blockIdx.x * (TSTEPS * 64) + ln15 * 4;
        const float* xb = x + (size_t)(bblk + ln15) * (TSTEPS * 4);
        s16x4 xv = {0,0,0,0};
        float4 xf4;
        if (XPRE) xv = *(const s16x4*)(xfp);       // lanes lg>0 replicate; their
        else      xf4 = *(const float4*)(xb);      // products hit zero B rows

        int k = 0;
        #pragma unroll 1
        for (int kb = 0; kb < TSTEPS / 2; ++kb) {  // 50 pairs: k=0..99, 100 bars
            L0STEP(k, 0);
            L0STEP(k + 1, 1);
            k += 2;
        }
        bar_lds();   // final: H1F ready

        if (tid < BC) {   // LN + FC (wave 0)
            const int b = tid;
            float hr[64];
            float mu = 0.f;
            #pragma unroll
            for (int q = 0; q < 64; ++q) { hr[q] = H1F[b * 65 + q]; mu += hr[q]; }
            mu *= (1.f / 64.f);
            float var = 0.f;
            #pragma unroll
            for (int q = 0; q < 64; ++q) { const float d = hr[q] - mu; var = fmaf(d, d, var); }
            var *= (1.f / 64.f);
            const float rs = rsqrtf(var + 1e-5f);
            float o0 = bfc[0], o1 = bfc[1];
            #pragma unroll
            for (int q = 0; q < 64; ++q) {
                const float nk = (hr[q] - mu) * rs * gam[q] + bet[q];
                o0 = fmaf(nk, Wfc[q],      o0);
                o1 = fmaf(nk, Wfc[64 + q], o1);
            }
            out[(size_t)(bblk + b) * 2 + 0] = o0;
            out[(size_t)(bblk + b) * 2 + 1] = o1;
        }
    } else {
        // ================= L1 consumer waves =================
        bf16x8 Bih1[4][2], Bhh1[4][2];
        #pragma unroll
        for (int G = 0; G < 4; ++G) {
            #pragma unroll
            for (int kc = 0; kc < 2; ++kc) {
                const int f = ((ug * 4 + G) * 2 + kc) * 512 + lane * 8;
                Bih1[G][kc] = *(const bf16x8*)(wsu + WS_WIH1_U + f);
                Bhh1[G][kc] = *(const bf16x8*)(wsu + WS_WHH1_U + f);
            }
        }
        f32x4 bV[4];
        #pragma unroll
        for (int G = 0; G < 4; ++G) {
            const float b = wsf[WS_B1_F + G * 64 + ug * 16 + ln15];
            bV[G] = (f32x4){b, b, b, b};
        }
        f32x2 c1v[2] = {{0.f,0.f},{0.f,0.f}};
        bf16x8 A0[2], A1[2];
        A1[0] = zfrag; A1[1] = zfrag;   // h1(-1)=0

        bar_lds();   // bar #1: h0(0) published
        A0[0] = *(const bf16x8*)(HBc + rbase);          // buf0[0] = h0(0)
        A0[1] = *(const bf16x8*)(HBc + rbase + 1024);

        int j = 0;
        #pragma unroll 1
        for (int jb = 0; jb < (TSTEPS - 2) / 2; ++jb) {  // 49 pairs: j=0..97
            L1STEP(j, 0);
            L1STEP(j + 1, 1);
            j += 2;
        }
        L1STEP(98, 0);   // 99 loop bars total; A0=h0(99), A1=h1(98) now loaded

        // final step j=99 -> H1F (f32), then final barrier
        {
            f32x4 acc1[4];
            #pragma unroll
            for (int G = 0; G < 4; ++G) {
                acc1[G] = MFMA(A0[0], Bih1[G][0], bV[G]);
                acc1[G] = MFMA(A0[1], Bih1[G][1], acc1[G]);
                acc1[G] = MFMA(A1[0], Bhh1[G][0], acc1[G]);
                acc1[G] = MFMA(A1[1], Bhh1[G][1], acc1[G]);
            }
            #pragma unroll
            for (int p = 0; p < 2; ++p) {
                const f32x2 h = lstm_cell(
                    (f32x2){acc1[0][2*p], acc1[0][2*p+1]},
                    (f32x2){acc1[1][2*p], acc1[1][2*p+1]},
                    (f32x2){acc1[2][2*p], acc1[2][2*p+1]},
                    (f32x2){acc1[3][2*p], acc1[3][2*p+1]}, c1v[p]);
                H1F[(lg * 4 + 2*p)     * 65 + ug * 16 + ln15] = h.x;
                H1F[(lg * 4 + 2*p + 1) * 65 + ug * 16 + ln15] = h.y;
            }
        }
        bar_lds();   // final
    }
}

extern "C" void kernel_launch(void* const* d_in, const int* in_sizes, int n_in,
                              void* d_out, int out_size, void* d_ws, size_t ws_size,
                              hipStream_t stream) {
    (void)in_sizes; (void)n_in; (void)out_size;
    const float* x    = (const float*)d_in[0];
    const float* Wih0 = (const float*)d_in[1];
    const float* Whh0 = (const float*)d_in[2];
    const float* bih0 = (const float*)d_in[3];
    const float* bhh0 = (const float*)d_in[4];
    const float* Wih1 = (const float*)d_in[5];
    const float* Whh1 = (const float*)d_in[6];
    const float* bih1 = (const float*)d_in[7];
    const float* bhh1 = (const float*)d_in[8];
    const float* gam  = (const float*)d_in[9];
    const float* bet  = (const float*)d_in[10];
    const float* Wfc  = (const float*)d_in[11];
    const float* bfc  = (const float*)d_in[12];
    unsigned short* wsu = (unsigned short*)d_ws;
    float*          wsf = (float*)d_ws;
    float* out = (float*)d_out;

    hipLaunchKernelGGL(reorder_w, dim3(96), dim3(256), 0, stream,
                       Wih0, Whh0, bih0, bhh0, Wih1, Whh1, bih1, bhh1, wsu, wsf);
    if (ws_size >= WS_NEED) {
        hipLaunchKernelGGL(prep_xfrag, dim3(NBLK * 16 * TSTEPS / 256), dim3(256), 0, stream,
                           x, wsu + WS_XF_U);
        hipLaunchKernelGGL((lstm2_mfma<true>), dim3(NBLK), dim3(512), 0, stream,
                           x, wsu, wsf, gam, bet, Wfc, bfc, out);
    } else {
        hipLaunchKernelGGL((lstm2_mfma<false>), dim3(NBLK), dim3(512), 0, stream,
                           x, wsu, wsf, gam, bet, Wfc, bfc, out);
    }
}